// Round 1
// baseline (3578.186 us; speedup 1.0000x reference)
//
#include <hip/hip_runtime.h>
#include <hip/hip_bf16.h>
#include <hip/hip_fp16.h>

// LSTM_RNN: B=128, T=512, E=256, U=512. R15 = R14 + XCC-VERIFIED L2-LOCAL
// EXCHANGE: the per-step critical path is exchange latency (MfmaUtil 7%,
// HBM 1.2%, step = 4.57us >> ~0.3us compute). R14 polled a volatile
// XCD-L2 flag on an UNVERIFIED round-robin bid->XCD assumption, with a
// 20-poll budget before falling back to the agent/LLC flag; all h data
// moved through agent scope (LLC RTs on drain + bulk load).
//   - NEW: one-time in-kernel XCD probe. Each WG publishes its
//     HW_REG_XCC_ID (s_getreg, m09) to XccTab (agent scope, zeroed by
//     hipMemsetAsync each launch -> no cross-launch staleness). All 128
//     WGs are co-resident (1 wg/CU), so every WG gathers all 128 tags.
//     Verdict (uniform per domain, computed from identical global data):
//     fast iff {16 domain slices same XCC} AND {>=2 distinct XCCs in
//     grid} (sanity: a broken getreg reading a constant forces slow).
//   - FAST path: whole exchange in the shared XCD-L2 via volatile (sc0)
//     ops: h stores volatile (B4 drains to L2 not LLC), FlagA volatile
//     only (no budget), bulk slab loads volatile (L2 hit on producer's
//     dirty lines, ~200cy vs ~900cy LLC). SLOW path: agent-scope as in
//     R14 but polls FlagB directly (drops the 20 wasted FlagA polls).
//   - Mixed-path hazard (agent store + volatile read of a stale clean L2
//     line) is excluded by verdict uniformity per domain.
//   - head_kernel correctness: end-of-dispatch agent release writes back
//     dirty L2 lines, so fast-path L2-resident Hq is visible after the
//     kernel boundary (same ordering R14 already relied on).
//   - Everything else R14-verbatim: producer/consumer wave split (kh1 =
//     x-GEMM + h[256,512), kh0 = exchange + h[0,256) + epilogue), weights
//     in VGPRs, LDS padded to 96 KB -> 1 wg/CU, 3 barriers/step, parity
//     flags, dep-offset pinning, 0xAA poison-safe flag values.
// ws layout (~33.82 MiB):
//   X      fp16 [T][B][E]        @ 0          (33,554,432 B)
//   Hq     fp16 [2][8][16][512]  @ 33,554,432 (262,144 B)
//   FlagA  u32  [2][8][16]       @ 33,816,576 (1,024 B)  volatile/XCD-L2
//   FlagB  u32  [2][8][16]       @ 33,817,600 (1,024 B)  agent/LLC
//   XccTab u32  [128]            @ 33,818,624 (512 B)    memset 0/launch

#define B_ 128
#define T_ 512
#define E_ 256
#define U_ 512
#define NWG_ 128
#define HROW_ 516   // Hs row stride (halves)

typedef __attribute__((ext_vector_type(4))) _Float16 half4;
typedef __attribute__((ext_vector_type(4))) float floatx4;
typedef unsigned long long u64t;
typedef unsigned int u32t;

#define MFMA16 __builtin_amdgcn_mfma_f32_16x16x16f16

__device__ __forceinline__ float sigmf(float x) { return 1.0f / (1.0f + __expf(-x)); }
__device__ __forceinline__ float tanh_f(float x) { return 2.0f / (1.0f + __expf(-2.0f * x)) - 1.0f; }

// X[t][b][e] = (fp16) emb[sentence[b][t]][e]; one thread = 8 elements.
__global__ void prep_x_kernel(const int* __restrict__ sent,
                              const float* __restrict__ emb,
                              _Float16* __restrict__ X) {
  int gid = blockIdx.x * blockDim.x + threadIdx.x;  // 2,097,152 total
  int e8 = gid & 31;
  int row = gid >> 5;         // row = t*128 + b
  int b = row & 127;
  int t = row >> 7;
  int word = sent[b * T_ + t];
  const float* src = emb + (size_t)word * E_ + e8 * 8;
  float4 v0 = *(const float4*)(src);
  float4 v1 = *(const float4*)(src + 4);
  _Float16 o[8] = {(_Float16)v0.x, (_Float16)v0.y, (_Float16)v0.z, (_Float16)v0.w,
                   (_Float16)v1.x, (_Float16)v1.y, (_Float16)v1.z, (_Float16)v1.w};
  _Float16* dst = X + (size_t)row * E_ + e8 * 8;
  *(half4*)dst = *(half4*)o;
  *(half4*)(dst + 4) = *(half4*)(o + 4);
}

__global__ __launch_bounds__(512, 1) void lstm_kernel(
    const _Float16* __restrict__ X,
    const float* __restrict__ Wx, const float* __restrict__ Wh,
    const float* __restrict__ bias,
    _Float16* __restrict__ Hq, u32t* FlagA, u32t* FlagB, u32t* XccTab) {
  // LDS: Hs [16][HROW_] fp16 (16,512) | Rs float[4][512] (8,192) |
  // xl u32[128] (512) = 25,216 used; block padded to 96 KB for 1 wg/CU.
  __shared__ __align__(16) char smem[98304];
  _Float16* Hs = (_Float16*)smem;
  float* Rs = (float*)(smem + 16512);
  u32t* xl = (u32t*)(smem + 24704);

  const int bid = blockIdx.x;
  const int d = bid & 7;    // domain: rows d*16 .. d*16+15 (one XCD under RR)
  const int s = bid >> 3;   // unit slice: units s*32 .. s*32+31
  const int tid = threadIdx.x;
  const int lane = tid & 63;
  const int wave = tid >> 6;      // 8 waves
  const int p16 = lane & 15;
  const int quad = lane >> 4;
  const int sg = wave & 3;        // unit subgroup (8 units)
  const int kh = wave >> 2;       // 0: exchange + h[0,256) + epilogue
                                  // 1: x-GEMM + h[256,512)

  // ---- one-time XCD-mapping probe ----
  // hwreg(HW_REG_XCC_ID=20, offset=0, size=32) -> imm = (31<<11)|20 = 63508
  if (tid == 0) {
    u32t myx = (u32t)__builtin_amdgcn_s_getreg(63508) & 0xFFu;
    __hip_atomic_store(XccTab + bid, 0x5A5A0000u | myx, __ATOMIC_RELAXED,
                       __HIP_MEMORY_SCOPE_AGENT);
  }
  if (wave == 0) {
    u32t v0, v1;
    for (;;) {
      v0 = __hip_atomic_load(XccTab + lane, __ATOMIC_RELAXED,
                             __HIP_MEMORY_SCOPE_AGENT);
      v1 = __hip_atomic_load(XccTab + 64 + lane, __ATOMIC_RELAXED,
                             __HIP_MEMORY_SCOPE_AGENT);
      if (__all(((v0 >> 16) == 0x5A5Au) & ((v1 >> 16) == 0x5A5Au))) break;
      __builtin_amdgcn_s_sleep(8);
    }
    xl[lane] = v0;
    xl[lane + 64] = v1;
  }
  __syncthreads();
  int fastv;
  {
    const u32t ref = xl[d];
    bool dom = true;
    for (int j = 1; j < 16; ++j) dom = dom && (xl[d + 8 * j] == ref);
    bool sane = false;  // getreg sanity: a constant-reading getreg -> slow
    const u32t z0 = xl[0];
    for (int e = 1; e < 128; ++e) sane = sane || (xl[e] != z0);
    fastv = (dom && sane) ? 1 : 0;
  }
  const bool fastp = (bool)__builtin_amdgcn_readfirstlane(fastv);

  // ---- one-time: gather this wave's B-fragments into VGPRs ----
  // kh0: 16 h-blocks (cols 0..255)   -> b0r[i], kb = 16+i,  i in [0,16)
  // kh1: 16 x-blocks + 16 h-blocks (cols 256..511)
  //      -> b0r[i]: i<16: kb = i (x); i>=16: kb = 16+i (h hi), i in [0,32)
  const int C0 = ((p16 >> 3) & 1) * 512 + s * 32 + sg * 8 + (p16 & 7);  // i/f
  const int C1 = C0 + 1024;                                             // g/o
  half4 b0r[32], b1r[32];
  if (kh == 0) {
#pragma unroll
    for (int i = 0; i < 16; ++i) {
      int kb = 16 + i;
#pragma unroll
      for (int j = 0; j < 4; ++j) {
        int gk = kb * 16 + quad * 4 + j;
        b0r[i][j] = (_Float16)Wh[(size_t)(gk - E_) * 2048 + C0];
        b1r[i][j] = (_Float16)Wh[(size_t)(gk - E_) * 2048 + C1];
      }
    }
  } else {
#pragma unroll
    for (int i = 0; i < 32; ++i) {
      int kb = (i < 16) ? i : (16 + i);
#pragma unroll
      for (int j = 0; j < 4; ++j) {
        int gk = kb * 16 + quad * 4 + j;
        float w0 = (gk < E_) ? Wx[(size_t)gk * 2048 + C0]
                             : Wh[(size_t)(gk - E_) * 2048 + C0];
        float w1 = (gk < E_) ? Wx[(size_t)gk * 2048 + C1]
                             : Wh[(size_t)(gk - E_) * 2048 + C1];
        b0r[i][j] = (_Float16)w0;
        b1r[i][j] = (_Float16)w1;
      }
    }
  }

  const bool lo = (p16 < 8);
  const int uo = p16 & 7;
  const int gu = s * 32 + sg * 8 + uo;               // global unit id
  const float bias0 = bias[(lo ? 0 : 512) + gu];     // i or f
  const float bias1 = bias[(lo ? 1024 : 1536) + gu]; // g or o

  float cst[4] = {0.f, 0.f, 0.f, 0.f};  // c-state (kh0 waves, lo lanes)

  const int brow = d * 16 + p16;   // A-frag batch row
  const int ko = quad * 4;

  for (int t = 0; t < T_; ++t) {
    const int pin = t & 1, pout = pin ^ 1;

    floatx4 acc0 = {0.f, 0.f, 0.f, 0.f};
    floatx4 acc1 = {0.f, 0.f, 0.f, 0.f};

    if (kh == 1) {
      // ---- x-GEMM (kh1 only): 16 K16-blocks ----
      const _Float16* xr = X + ((size_t)t * B_ + brow) * E_ + ko;
#pragma unroll
      for (int i = 0; i < 16; ++i) {
        half4 a = *(const half4*)(xr + i * 16);
        acc0 = MFMA16(a, b0r[i], acc0, 0, 0, 0);
        acc1 = MFMA16(a, b1r[i], acc1, 0, 0, 0);
      }
    } else if (t > 0) {
      // ---- exchange (kh0 only): poll + bulk + stage, overlaps kh1's x ----
      const u32t tgt = (u32t)t;
      u32t v;
      if (fastp) {
        // verified same-XCD: volatile poll on the shared L2, no fallback
        const volatile u32t* fa = FlagA + (size_t)(pin * 8 + d) * 16;
        for (;;) {
          v = fa[p16];
          if (__all(v == tgt)) break;
          __builtin_amdgcn_s_sleep(1);
        }
      } else {
        // unverified mapping: agent/LLC flag directly (no wasted budget)
        const u32t* fb = FlagB + (size_t)(pin * 8 + d) * 16;
        for (;;) {
          v = __hip_atomic_load(fb + p16, __ATOMIC_RELAXED,
                                __HIP_MEMORY_SCOPE_AGENT);
          if (__all(v == tgt)) break;
          __builtin_amdgcn_s_sleep(1);
        }
      }
      const size_t dep = (size_t)(v >> 16);  // always 0; addr dependency

      // bulk: 4 rows/wave (rows wave*4 .. wave*4+3), 8 chunks of 512B
      const _Float16* hq =
          Hq + ((size_t)(pin * 8 + d) * 16 + wave * 4) * 512 + dep;
      u64t hv[8];
      if (fastp) {
#pragma unroll
        for (int j = 0; j < 8; ++j) {
          size_t idx = (size_t)(j >> 1) * 128 + (j & 1) * 64 + lane;
          hv[j] = *((const volatile u64t*)hq + idx);   // sc0: L2 hit
        }
      } else {
#pragma unroll
        for (int j = 0; j < 8; ++j) {
          size_t idx = (size_t)(j >> 1) * 128 + (j & 1) * 64 + lane;
          hv[j] = __hip_atomic_load((const u64t*)hq + idx, __ATOMIC_RELAXED,
                                    __HIP_MEMORY_SCOPE_AGENT);
        }
      }
#pragma unroll
      for (int j = 0; j < 8; ++j) {
        int r = wave * 4 + (j >> 1), half = j & 1;
        *(u64t*)(Hs + r * HROW_ + half * 256 + lane * 4) = hv[j];
      }
    }
    __syncthreads();  // B2: slab ready + x partial-accs in flight

    if (t > 0) {
      // ---- h-GEMM from slab: kh0 -> cols [0,256), kh1 -> [256,512) ----
#pragma unroll
      for (int i = 0; i < 16; ++i) {
        int hk = kh * 16 + i;
        half4 a = *(const half4*)(Hs + p16 * HROW_ + hk * 16 + ko);
        const int wi = (kh == 0) ? i : (16 + i);
        acc0 = MFMA16(a, b0r[wi], acc0, 0, 0, 0);
        acc1 = MFMA16(a, b1r[wi], acc1, 0, 0, 0);
      }
    }

    // ---- kh1 partials -> Rs ----
    if (kh == 1) {
      float* wb = Rs + sg * 512;
      *(floatx4*)(wb + lane * 4) = acc0;
      *(floatx4*)(wb + 256 + lane * 4) = acc1;
    }
    __syncthreads();  // B3: partials ready

    // ---- epilogue (kh0): reduce, gates, fp16 publish ----
    if (kh == 0) {
      const float* rb = Rs + sg * 512;
      floatx4 z0v = acc0 + *(const floatx4*)(rb + lane * 4);
      floatx4 z1v = acc1 + *(const floatx4*)(rb + 256 + lane * 4);
#pragma unroll
      for (int r = 0; r < 4; ++r) {
        float z0 = z0v[r] + bias0;  // i (lo) / f (hi)
        float z1 = z1v[r] + bias1;  // g (lo) / o (hi)
        float s0 = sigmf(z0);
        float s1 = lo ? tanh_f(z1) : sigmf(z1);
        float prod = s0 * s1;                          // i*g on lo lanes
        float fg = __shfl_xor(lo ? prod : s0, 8, 64);  // lo receives f
        float og = __shfl_xor(s1, 8, 64);              // lo receives o
        if (lo) {
          float cn = fg * cst[r] + prod;
          cst[r] = cn;
          float h = og * tanh_f(cn);
          int rowl = quad * 4 + r;                     // local row in domain
          _Float16 hf16 = (_Float16)h;
          unsigned short hb = __builtin_bit_cast(unsigned short, hf16);
          unsigned short* hp =
              (unsigned short*)(Hq +
                                ((size_t)(pout * 8 + d) * 16 + rowl) * 512 + gu);
          if (fastp) {
            *(volatile unsigned short*)hp = hb;        // stays in XCD-L2
          } else {
            __hip_atomic_store(hp, hb, __ATOMIC_RELAXED,
                               __HIP_MEMORY_SCOPE_AGENT);
          }
        }
      }
    }

    // ---- B4: drain vmcnt(0) for ALL waves (h landed) -> flag ----
    __syncthreads();
    if (tid == 0) {
      size_t fo = (size_t)(pout * 8 + d) * 16 + s;
      if (fastp) {
        *(volatile u32t*)(FlagA + fo) = (u32t)(t + 1);     // XCD-L2 copy
      } else {
        __hip_atomic_store(FlagB + fo, (u32t)(t + 1), __ATOMIC_RELAXED,
                           __HIP_MEMORY_SCOPE_AGENT);      // LLC copy
      }
    }
  }
}

// MLP head: one block per batch row. h(512)->relu 128->relu 64->sigmoid 1.
// T=512 even -> final h in Hq parity 0. Kernel boundary orders prior stores
// (end-of-dispatch agent release writes back dirty L2 lines).
__global__ void head_kernel(const _Float16* __restrict__ Hq,
                            const float* __restrict__ W1, const float* __restrict__ b1,
                            const float* __restrict__ W2, const float* __restrict__ b2,
                            const float* __restrict__ W3, const float* __restrict__ b3,
                            float* __restrict__ out) {
  __shared__ float hs[512];
  __shared__ float h1[128];
  __shared__ float h2[64];
  int row = blockIdx.x;
  int tid = threadIdx.x;  // 128 threads
  int dd = row >> 4, rr = row & 15;
  const _Float16* hrow = Hq + ((size_t)dd * 16 + rr) * 512;
  for (int k = tid; k < 512; k += 128) hs[k] = (float)hrow[k];
  __syncthreads();
  float a = b1[tid];
  for (int k = 0; k < 512; ++k) a += hs[k] * W1[k * 128 + tid];
  h1[tid] = fmaxf(a, 0.0f);
  __syncthreads();
  if (tid < 64) {
    float a2 = b2[tid];
    for (int k = 0; k < 128; ++k) a2 += h1[k] * W2[k * 64 + tid];
    h2[tid] = fmaxf(a2, 0.0f);
  }
  __syncthreads();
  if (tid == 0) {
    float a3 = b3[0];
    for (int k = 0; k < 64; ++k) a3 += h2[k] * W3[k];
    out[row] = 1.0f / (1.0f + __expf(-a3));
  }
}

extern "C" void kernel_launch(void* const* d_in, const int* in_sizes, int n_in,
                              void* d_out, int out_size, void* d_ws, size_t ws_size,
                              hipStream_t stream) {
  const int* sent = (const int*)d_in[0];
  const float* emb = (const float*)d_in[1];
  const float* Wx = (const float*)d_in[2];
  const float* Wh = (const float*)d_in[3];
  const float* b = (const float*)d_in[4];
  const float* W1 = (const float*)d_in[5];
  const float* b1 = (const float*)d_in[6];
  const float* W2 = (const float*)d_in[7];
  const float* b2 = (const float*)d_in[8];
  const float* W3 = (const float*)d_in[9];
  const float* b3 = (const float*)d_in[10];
  float* out = (float*)d_out;

  char* ws = (char*)d_ws;
  _Float16* X = (_Float16*)(ws);
  _Float16* Hq = (_Float16*)(ws + (size_t)33554432);
  u32t* FlagA = (u32t*)(ws + (size_t)33554432 + 262144);
  u32t* FlagB = (u32t*)(ws + (size_t)33554432 + 263168);
  u32t* XccTab = (u32t*)(ws + (size_t)33554432 + 264192);

  // Fresh XCD-probe table every launch (graph-capturable stream op).
  hipMemsetAsync(XccTab, 0, 512, stream);
  prep_x_kernel<<<8192, 256, 0, stream>>>(sent, emb, X);
  lstm_kernel<<<NWG_, 512, 0, stream>>>(X, Wx, Wh, b, Hq, FlagA, FlagB, XccTab);
  head_kernel<<<128, 128, 0, stream>>>(Hq, W1, b1, W2, b2, W3, b3, out);
}

// Round 3
// 3028.690 us; speedup vs baseline: 1.1814x; 1.1814x over previous
//
#include <hip/hip_runtime.h>
#include <hip/hip_bf16.h>
#include <hip/hip_fp16.h>

// LSTM_RNN: B=128, T=512, E=256, U=512. R17 = R16 + GUARANTEED-PROGRESS
// FLAGS (R14's dual-publish + budget fallback restored).
//   R16 post-mortem: hang (no counters). Only un-fallback'd novelty was the
//   sc0-store -> sc0-load FLAG channel; if sc0 stores write around the
//   XCD-L2 (or consumer sc0 loads hit a stale clean L2 line), the poll
//   spins forever. R14 was immune via its agent-flag fallback. Data path
//   (plain write-through h stores -> shared L2; sc0 bulk reads) is not
//   progress-critical and stays.
//   - Producer (tid0, after B4 vmcnt drain): publish BOTH FlagB (agent/LLC,
//     proven channel) and FlagA (sc0). Fire-and-forget; acks overlap the
//     consumer polls that fail once anyway in lockstep.
//   - Consumer: budget-16 sc0 polls on FlagA (~300cy each, XCD-L2), then
//     fall back to agent polls on FlagB (~900cy, R14-proven). Either flag
//     implies h committed to the shared L2 (B4 drained vmcnt before the
//     stores) -> sc0 bulk reads are correct under the same-XCD verdict in
//     both cases. Hang-proof by construction.
//   - Bulk slab: ONE asm block, 8x global_load_dwordx2 sc0 off one base
//     with imm offsets 0..3584, single vmcnt(0) -> pipelined, ~1 L2 RT.
//   - h stores: plain (L1 write-through -> dirty in local XCD-L2).
//   - SLOW path (verdict fails): R14 agent/LLC semantics, FlagB only.
//   - Verdict per domain uniform (identical global data) -> no mixed paths.
//     Sanity guard: >=2 distinct XCCs required, else slow.
//   - head_kernel: end-of-dispatch agent release writes back dirty L2, so
//     L2-resident Hq is visible across the kernel boundary.
// ws layout (~33.82 MiB):
//   X      fp16 [T][B][E]        @ 0          (33,554,432 B)
//   Hq     fp16 [2][8][16][512]  @ 33,554,432 (262,144 B)
//   FlagA  u32  [2][8][16]       @ 33,816,576 (1,024 B)  sc0/XCD-L2
//   FlagB  u32  [2][8][16]       @ 33,817,600 (1,024 B)  agent/LLC
//   XccTab u32  [128]            @ 33,818,624 (512 B)    memset 0/launch

#define B_ 128
#define T_ 512
#define E_ 256
#define U_ 512
#define NWG_ 128
#define HROW_ 516   // Hs row stride (halves)

typedef __attribute__((ext_vector_type(4))) _Float16 half4;
typedef __attribute__((ext_vector_type(4))) float floatx4;
typedef unsigned long long u64t;
typedef unsigned int u32t;

#define MFMA16 __builtin_amdgcn_mfma_f32_16x16x16f16

__device__ __forceinline__ float sigmf(float x) { return 1.0f / (1.0f + __expf(-x)); }
__device__ __forceinline__ float tanh_f(float x) { return 2.0f / (1.0f + __expf(-2.0f * x)) - 1.0f; }

// sc0-only (bypass L1, XCD-L2) primitives. Only used under the same-XCD
// verdict; never progress-critical (agent fallback always available).
__device__ __forceinline__ u32t load_u32_sc0(const u32t* p) {
  u32t r;
  asm volatile("global_load_dword %0, %1, off sc0\n\t"
               "s_waitcnt vmcnt(0)"
               : "=v"(r) : "v"(p) : "memory");
  return r;
}
__device__ __forceinline__ void store_u32_sc0(u32t* p, u32t v) {
  asm volatile("global_store_dword %0, %1, off sc0" :: "v"(p), "v"(v)
               : "memory");
}

// X[t][b][e] = (fp16) emb[sentence[b][t]][e]; one thread = 8 elements.
__global__ void prep_x_kernel(const int* __restrict__ sent,
                              const float* __restrict__ emb,
                              _Float16* __restrict__ X) {
  int gid = blockIdx.x * blockDim.x + threadIdx.x;  // 2,097,152 total
  int e8 = gid & 31;
  int row = gid >> 5;         // row = t*128 + b
  int b = row & 127;
  int t = row >> 7;
  int word = sent[b * T_ + t];
  const float* src = emb + (size_t)word * E_ + e8 * 8;
  float4 v0 = *(const float4*)(src);
  float4 v1 = *(const float4*)(src + 4);
  _Float16 o[8] = {(_Float16)v0.x, (_Float16)v0.y, (_Float16)v0.z, (_Float16)v0.w,
                   (_Float16)v1.x, (_Float16)v1.y, (_Float16)v1.z, (_Float16)v1.w};
  _Float16* dst = X + (size_t)row * E_ + e8 * 8;
  *(half4*)dst = *(half4*)o;
  *(half4*)(dst + 4) = *(half4*)(o + 4);
}

__global__ __launch_bounds__(512, 1) void lstm_kernel(
    const _Float16* __restrict__ X,
    const float* __restrict__ Wx, const float* __restrict__ Wh,
    const float* __restrict__ bias,
    _Float16* __restrict__ Hq, u32t* FlagA, u32t* FlagB, u32t* XccTab) {
  // LDS: Hs [16][HROW_] fp16 (16,512) | Rs float[4][512] (8,192) |
  // xl u32[128] (512) = 25,216 used; block padded to 96 KB for 1 wg/CU.
  __shared__ __align__(16) char smem[98304];
  _Float16* Hs = (_Float16*)smem;
  float* Rs = (float*)(smem + 16512);
  u32t* xl = (u32t*)(smem + 24704);

  const int bid = blockIdx.x;
  const int d = bid & 7;    // domain: rows d*16 .. d*16+15 (one XCD, verified)
  const int s = bid >> 3;   // unit slice: units s*32 .. s*32+31
  const int tid = threadIdx.x;
  const int lane = tid & 63;
  const int wave = tid >> 6;      // 8 waves
  const int p16 = lane & 15;
  const int quad = lane >> 4;
  const int sg = wave & 3;        // unit subgroup (8 units)
  const int kh = wave >> 2;       // 0: exchange + h[0,256) + epilogue
                                  // 1: x-GEMM + h[256,512)

  // ---- one-time XCD-mapping probe ----
  // hwreg(HW_REG_XCC_ID=20, offset=0, size=32) -> imm = (31<<11)|20 = 63508
  if (tid == 0) {
    u32t myx = (u32t)__builtin_amdgcn_s_getreg(63508) & 0xFFu;
    __hip_atomic_store(XccTab + bid, 0x5A5A0000u | myx, __ATOMIC_RELAXED,
                       __HIP_MEMORY_SCOPE_AGENT);
  }
  if (wave == 0) {
    u32t v0, v1;
    for (;;) {
      v0 = __hip_atomic_load(XccTab + lane, __ATOMIC_RELAXED,
                             __HIP_MEMORY_SCOPE_AGENT);
      v1 = __hip_atomic_load(XccTab + 64 + lane, __ATOMIC_RELAXED,
                             __HIP_MEMORY_SCOPE_AGENT);
      if (__all(((v0 >> 16) == 0x5A5Au) & ((v1 >> 16) == 0x5A5Au))) break;
      __builtin_amdgcn_s_sleep(8);
    }
    xl[lane] = v0;
    xl[lane + 64] = v1;
  }
  __syncthreads();
  int fastv;
  {
    const u32t ref = xl[d];
    bool dom = true;
    for (int j = 1; j < 16; ++j) dom = dom && (xl[d + 8 * j] == ref);
    bool sane = false;  // getreg sanity: a constant-reading getreg -> slow
    const u32t z0 = xl[0];
    for (int e = 1; e < 128; ++e) sane = sane || (xl[e] != z0);
    fastv = (dom && sane) ? 1 : 0;
  }
  const bool fastp = (bool)__builtin_amdgcn_readfirstlane(fastv);

  // ---- one-time: gather this wave's B-fragments into VGPRs ----
  // kh0: 16 h-blocks (cols 0..255)   -> b0r[i], kb = 16+i,  i in [0,16)
  // kh1: 16 x-blocks + 16 h-blocks (cols 256..511)
  //      -> b0r[i]: i<16: kb = i (x); i>=16: kb = 16+i (h hi), i in [0,32)
  const int C0 = ((p16 >> 3) & 1) * 512 + s * 32 + sg * 8 + (p16 & 7);  // i/f
  const int C1 = C0 + 1024;                                             // g/o
  half4 b0r[32], b1r[32];
  if (kh == 0) {
#pragma unroll
    for (int i = 0; i < 16; ++i) {
      int kb = 16 + i;
#pragma unroll
      for (int j = 0; j < 4; ++j) {
        int gk = kb * 16 + quad * 4 + j;
        b0r[i][j] = (_Float16)Wh[(size_t)(gk - E_) * 2048 + C0];
        b1r[i][j] = (_Float16)Wh[(size_t)(gk - E_) * 2048 + C1];
      }
    }
  } else {
#pragma unroll
    for (int i = 0; i < 32; ++i) {
      int kb = (i < 16) ? i : (16 + i);
#pragma unroll
      for (int j = 0; j < 4; ++j) {
        int gk = kb * 16 + quad * 4 + j;
        float w0 = (gk < E_) ? Wx[(size_t)gk * 2048 + C0]
                             : Wh[(size_t)(gk - E_) * 2048 + C0];
        float w1 = (gk < E_) ? Wx[(size_t)gk * 2048 + C1]
                             : Wh[(size_t)(gk - E_) * 2048 + C1];
        b0r[i][j] = (_Float16)w0;
        b1r[i][j] = (_Float16)w1;
      }
    }
  }

  const bool lo = (p16 < 8);
  const int uo = p16 & 7;
  const int gu = s * 32 + sg * 8 + uo;               // global unit id
  const float bias0 = bias[(lo ? 0 : 512) + gu];     // i or f
  const float bias1 = bias[(lo ? 1024 : 1536) + gu]; // g or o

  float cst[4] = {0.f, 0.f, 0.f, 0.f};  // c-state (kh0 waves, lo lanes)

  const int brow = d * 16 + p16;   // A-frag batch row
  const int ko = quad * 4;

  for (int t = 0; t < T_; ++t) {
    const int pin = t & 1, pout = pin ^ 1;

    floatx4 acc0 = {0.f, 0.f, 0.f, 0.f};
    floatx4 acc1 = {0.f, 0.f, 0.f, 0.f};

    if (kh == 1) {
      // ---- x-GEMM (kh1 only): 16 K16-blocks ----
      const _Float16* xr = X + ((size_t)t * B_ + brow) * E_ + ko;
#pragma unroll
      for (int i = 0; i < 16; ++i) {
        half4 a = *(const half4*)(xr + i * 16);
        acc0 = MFMA16(a, b0r[i], acc0, 0, 0, 0);
        acc1 = MFMA16(a, b1r[i], acc1, 0, 0, 0);
      }
    } else if (t > 0) {
      // ---- exchange (kh0 only): poll + bulk + stage, overlaps kh1's x ----
      const u32t tgt = (u32t)t;
      u32t v;
      if (fastp) {
        // budget-16 sc0 polls (XCD-L2, ~300cy), then agent/LLC fallback
        // (R14-proven progress channel; producer dual-publishes).
        const u32t* fa = FlagA + (size_t)(pin * 8 + d) * 16;
        const u32t* fb = FlagB + (size_t)(pin * 8 + d) * 16;
        int budget = 16;
        for (;;) {
          v = (budget > 0)
                  ? load_u32_sc0(fa + p16)
                  : __hip_atomic_load(fb + p16, __ATOMIC_RELAXED,
                                      __HIP_MEMORY_SCOPE_AGENT);
          if (__all(v == tgt)) break;
          --budget;
          __builtin_amdgcn_s_sleep(1);
        }
      } else {
        // unverified mapping: agent/LLC flag only
        const u32t* fb = FlagB + (size_t)(pin * 8 + d) * 16;
        for (;;) {
          v = __hip_atomic_load(fb + p16, __ATOMIC_RELAXED,
                                __HIP_MEMORY_SCOPE_AGENT);
          if (__all(v == tgt)) break;
          __builtin_amdgcn_s_sleep(1);
        }
      }
      const size_t dep = (size_t)(v >> 16);  // always 0; addr dependency

      // bulk: 4 rows/wave (rows wave*4 .. wave*4+3), 8 chunks of 512B
      const _Float16* hq =
          Hq + ((size_t)(pin * 8 + d) * 16 + wave * 4) * 512 + dep;
      u64t hv[8];
      if (fastp) {
        // ONE asm block: 8 pipelined sc0 loads (imm offsets), one vmcnt(0).
        // byte offsets: (j>>1)*1024 + (j&1)*512 relative to base+lane*8 =
        // exactly the slow path's idx=(j>>1)*128+(j&1)*64+lane u64s.
        const u64t* hqb = (const u64t*)hq + lane;
        u64t h0, h1, h2, h3, h4, h5, h6, h7;
        asm volatile(
            "global_load_dwordx2 %0, %8, off sc0\n\t"
            "global_load_dwordx2 %1, %8, off offset:512 sc0\n\t"
            "global_load_dwordx2 %2, %8, off offset:1024 sc0\n\t"
            "global_load_dwordx2 %3, %8, off offset:1536 sc0\n\t"
            "global_load_dwordx2 %4, %8, off offset:2048 sc0\n\t"
            "global_load_dwordx2 %5, %8, off offset:2560 sc0\n\t"
            "global_load_dwordx2 %6, %8, off offset:3072 sc0\n\t"
            "global_load_dwordx2 %7, %8, off offset:3584 sc0\n\t"
            "s_waitcnt vmcnt(0)"
            : "=&v"(h0), "=&v"(h1), "=&v"(h2), "=&v"(h3),
              "=&v"(h4), "=&v"(h5), "=&v"(h6), "=&v"(h7)
            : "v"(hqb)
            : "memory");
        hv[0] = h0; hv[1] = h1; hv[2] = h2; hv[3] = h3;
        hv[4] = h4; hv[5] = h5; hv[6] = h6; hv[7] = h7;
      } else {
#pragma unroll
        for (int j = 0; j < 8; ++j) {
          size_t idx = (size_t)(j >> 1) * 128 + (j & 1) * 64 + lane;
          hv[j] = __hip_atomic_load((const u64t*)hq + idx, __ATOMIC_RELAXED,
                                    __HIP_MEMORY_SCOPE_AGENT);
        }
      }
#pragma unroll
      for (int j = 0; j < 8; ++j) {
        int r = wave * 4 + (j >> 1), half = j & 1;
        *(u64t*)(Hs + r * HROW_ + half * 256 + lane * 4) = hv[j];
      }
    }
    __syncthreads();  // B2: slab ready + x partial-accs in flight

    if (t > 0) {
      // ---- h-GEMM from slab: kh0 -> cols [0,256), kh1 -> [256,512) ----
#pragma unroll
      for (int i = 0; i < 16; ++i) {
        int hk = kh * 16 + i;
        half4 a = *(const half4*)(Hs + p16 * HROW_ + hk * 16 + ko);
        const int wi = (kh == 0) ? i : (16 + i);
        acc0 = MFMA16(a, b0r[wi], acc0, 0, 0, 0);
        acc1 = MFMA16(a, b1r[wi], acc1, 0, 0, 0);
      }
    }

    // ---- kh1 partials -> Rs ----
    if (kh == 1) {
      float* wb = Rs + sg * 512;
      *(floatx4*)(wb + lane * 4) = acc0;
      *(floatx4*)(wb + 256 + lane * 4) = acc1;
    }
    __syncthreads();  // B3: partials ready

    // ---- epilogue (kh0): reduce, gates, fp16 publish ----
    if (kh == 0) {
      const float* rb = Rs + sg * 512;
      floatx4 z0v = acc0 + *(const floatx4*)(rb + lane * 4);
      floatx4 z1v = acc1 + *(const floatx4*)(rb + 256 + lane * 4);
#pragma unroll
      for (int r = 0; r < 4; ++r) {
        float z0 = z0v[r] + bias0;  // i (lo) / f (hi)
        float z1 = z1v[r] + bias1;  // g (lo) / o (hi)
        float s0 = sigmf(z0);
        float s1 = lo ? tanh_f(z1) : sigmf(z1);
        float prod = s0 * s1;                          // i*g on lo lanes
        float fg = __shfl_xor(lo ? prod : s0, 8, 64);  // lo receives f
        float og = __shfl_xor(s1, 8, 64);              // lo receives o
        if (lo) {
          float cn = fg * cst[r] + prod;
          cst[r] = cn;
          float h = og * tanh_f(cn);
          int rowl = quad * 4 + r;                     // local row in domain
          _Float16 hf16 = (_Float16)h;
          unsigned short hb = __builtin_bit_cast(unsigned short, hf16);
          unsigned short* hp =
              (unsigned short*)(Hq +
                                ((size_t)(pout * 8 + d) * 16 + rowl) * 512 + gu);
          if (fastp) {
            // plain store: L1 write-through -> dirty in local XCD-L2;
            // B4 __syncthreads drains vmcnt(0) before the flags go out.
            *hp = hb;
          } else {
            __hip_atomic_store(hp, hb, __ATOMIC_RELAXED,
                               __HIP_MEMORY_SCOPE_AGENT);
          }
        }
      }
    }

    // ---- B4: drain vmcnt(0) for ALL waves (h committed) -> flags ----
    __syncthreads();
    if (tid == 0) {
      size_t fo = (size_t)(pout * 8 + d) * 16 + s;
      if (fastp) {
        // Dual-publish: agent/LLC first (progress guarantee), sc0 second
        // (fast channel). Consumer accepts either.
        __hip_atomic_store(FlagB + fo, (u32t)(t + 1), __ATOMIC_RELAXED,
                           __HIP_MEMORY_SCOPE_AGENT);
        store_u32_sc0(FlagA + fo, (u32t)(t + 1));
      } else {
        __hip_atomic_store(FlagB + fo, (u32t)(t + 1), __ATOMIC_RELAXED,
                           __HIP_MEMORY_SCOPE_AGENT);
      }
    }
  }
}

// MLP head: one block per batch row. h(512)->relu 128->relu 64->sigmoid 1.
// T=512 even -> final h in Hq parity 0. Kernel boundary orders prior stores
// (end-of-dispatch agent release writes back dirty L2 lines).
__global__ void head_kernel(const _Float16* __restrict__ Hq,
                            const float* __restrict__ W1, const float* __restrict__ b1,
                            const float* __restrict__ W2, const float* __restrict__ b2,
                            const float* __restrict__ W3, const float* __restrict__ b3,
                            float* __restrict__ out) {
  __shared__ float hs[512];
  __shared__ float h1[128];
  __shared__ float h2[64];
  int row = blockIdx.x;
  int tid = threadIdx.x;  // 128 threads
  int dd = row >> 4, rr = row & 15;
  const _Float16* hrow = Hq + ((size_t)dd * 16 + rr) * 512;
  for (int k = tid; k < 512; k += 128) hs[k] = (float)hrow[k];
  __syncthreads();
  float a = b1[tid];
  for (int k = 0; k < 512; ++k) a += hs[k] * W1[k * 128 + tid];
  h1[tid] = fmaxf(a, 0.0f);
  __syncthreads();
  if (tid < 64) {
    float a2 = b2[tid];
    for (int k = 0; k < 128; ++k) a2 += h1[k] * W2[k * 64 + tid];
    h2[tid] = fmaxf(a2, 0.0f);
  }
  __syncthreads();
  if (tid == 0) {
    float a3 = b3[0];
    for (int k = 0; k < 64; ++k) a3 += h2[k] * W3[k];
    out[row] = 1.0f / (1.0f + __expf(-a3));
  }
}

extern "C" void kernel_launch(void* const* d_in, const int* in_sizes, int n_in,
                              void* d_out, int out_size, void* d_ws, size_t ws_size,
                              hipStream_t stream) {
  const int* sent = (const int*)d_in[0];
  const float* emb = (const float*)d_in[1];
  const float* Wx = (const float*)d_in[2];
  const float* Wh = (const float*)d_in[3];
  const float* b = (const float*)d_in[4];
  const float* W1 = (const float*)d_in[5];
  const float* b1 = (const float*)d_in[6];
  const float* W2 = (const float*)d_in[7];
  const float* b2 = (const float*)d_in[8];
  const float* W3 = (const float*)d_in[9];
  const float* b3 = (const float*)d_in[10];
  float* out = (float*)d_out;

  char* ws = (char*)d_ws;
  _Float16* X = (_Float16*)(ws);
  _Float16* Hq = (_Float16*)(ws + (size_t)33554432);
  u32t* FlagA = (u32t*)(ws + (size_t)33554432 + 262144);
  u32t* FlagB = (u32t*)(ws + (size_t)33554432 + 263168);
  u32t* XccTab = (u32t*)(ws + (size_t)33554432 + 264192);

  // Fresh XCD-probe table every launch (graph-capturable stream op).
  hipMemsetAsync(XccTab, 0, 512, stream);
  prep_x_kernel<<<8192, 256, 0, stream>>>(sent, emb, X);
  lstm_kernel<<<NWG_, 512, 0, stream>>>(X, Wx, Wh, b, Hq, FlagA, FlagB, XccTab);
  head_kernel<<<128, 128, 0, stream>>>(Hq, W1, b1, W2, b2, W3, b3, out);
}

// Round 4
// 3027.245 us; speedup vs baseline: 1.1820x; 1.0005x over previous
//
#include <hip/hip_runtime.h>
#include <hip/hip_bf16.h>
#include <hip/hip_fp16.h>

// LSTM_RNN: B=128, T=512, E=256, U=512. R18 = R17 + L2-ATOMIC FLAG CHANNEL.
//   R17 counters: data path is proven L2-resident (WRITE_SIZE 136MB->3.3MB,
//   FETCH 76->42MB, absmax 2^-9 pass) but dur REGRESSED 4.49->5.75us/step:
//   the sc0 flag channel never fires (R16 hang: sc0 STORES write around L2;
//   sc0 LOADS keep hitting the stale clean line), so every step burned 16
//   dead polls (~2.4us) before the agent fallback. +2.4-0.6(data gains)=+1.3
//   us/step — matches measurement exactly.
//   - NEW flag channel, both halves using MECHANISMS PROVEN ON THIS CHIP:
//     * publish: __hip_atomic_store(...,WORKGROUP) -> plain store, write-
//       through INTO local L2 dirty — identical mechanism to the h-data
//       stores R17 proved visible to same-XCD sc0 readers.
//     * poll: __hip_atomic_fetch_add(flag,0,WORKGROUP) -> global_atomic_add
//       sc0 (return-old). Atomics execute AT the L2, cannot be served by a
//       stale upstream structure like R16's sc0 load. Same-XCD (probe-
//       verified) => same physical L2 => ~300cy RT vs agent ~900cy.
//   - Progress guarantee retained: dual-publish FlagB (agent/LLC) + budget-
//     16 fallback poll. Worst case = R17-like slow-but-passing, never hang.
//   - Data path R17-verbatim: plain write-through h stores (L2 dirty), ONE
//     asm block of 8 pipelined sc0 bulk loads + single vmcnt(0), sc0 only
//     under the same-XCD verdict.
//   - SLOW path (verdict fails): R14 agent/LLC semantics, FlagB only.
//   - head_kernel: end-of-dispatch release writes back dirty L2 -> Hq
//     visible across the kernel boundary.
// ws layout (~33.82 MiB):
//   X      fp16 [T][B][E]        @ 0          (33,554,432 B)
//   Hq     fp16 [2][8][16][512]  @ 33,554,432 (262,144 B)
//   FlagA  u32  [2][8][16]       @ 33,816,576 (1,024 B)  L2-local channel
//   FlagB  u32  [2][8][16]       @ 33,817,600 (1,024 B)  agent/LLC channel
//   XccTab u32  [128]            @ 33,818,624 (512 B)    memset 0/launch

#define B_ 128
#define T_ 512
#define E_ 256
#define U_ 512
#define NWG_ 128
#define HROW_ 516   // Hs row stride (halves)

typedef __attribute__((ext_vector_type(4))) _Float16 half4;
typedef __attribute__((ext_vector_type(4))) float floatx4;
typedef unsigned long long u64t;
typedef unsigned int u32t;

#define MFMA16 __builtin_amdgcn_mfma_f32_16x16x16f16

__device__ __forceinline__ float sigmf(float x) { return 1.0f / (1.0f + __expf(-x)); }
__device__ __forceinline__ float tanh_f(float x) { return 2.0f / (1.0f + __expf(-2.0f * x)) - 1.0f; }

// L2-local flag poll: atomic RMW executes at the XCD-L2 (workgroup scope ->
// no sc1), returns old value. Only meaningful under the same-XCD verdict.
__device__ __forceinline__ u32t poll_l2(u32t* p) {
  return __hip_atomic_fetch_add(p, 0u, __ATOMIC_RELAXED,
                                __HIP_MEMORY_SCOPE_WORKGROUP);
}

// X[t][b][e] = (fp16) emb[sentence[b][t]][e]; one thread = 8 elements.
__global__ void prep_x_kernel(const int* __restrict__ sent,
                              const float* __restrict__ emb,
                              _Float16* __restrict__ X) {
  int gid = blockIdx.x * blockDim.x + threadIdx.x;  // 2,097,152 total
  int e8 = gid & 31;
  int row = gid >> 5;         // row = t*128 + b
  int b = row & 127;
  int t = row >> 7;
  int word = sent[b * T_ + t];
  const float* src = emb + (size_t)word * E_ + e8 * 8;
  float4 v0 = *(const float4*)(src);
  float4 v1 = *(const float4*)(src + 4);
  _Float16 o[8] = {(_Float16)v0.x, (_Float16)v0.y, (_Float16)v0.z, (_Float16)v0.w,
                   (_Float16)v1.x, (_Float16)v1.y, (_Float16)v1.z, (_Float16)v1.w};
  _Float16* dst = X + (size_t)row * E_ + e8 * 8;
  *(half4*)dst = *(half4*)o;
  *(half4*)(dst + 4) = *(half4*)(o + 4);
}

__global__ __launch_bounds__(512, 1) void lstm_kernel(
    const _Float16* __restrict__ X,
    const float* __restrict__ Wx, const float* __restrict__ Wh,
    const float* __restrict__ bias,
    _Float16* __restrict__ Hq, u32t* FlagA, u32t* FlagB, u32t* XccTab) {
  // LDS: Hs [16][HROW_] fp16 (16,512) | Rs float[4][512] (8,192) |
  // xl u32[128] (512) = 25,216 used; block padded to 96 KB for 1 wg/CU.
  __shared__ __align__(16) char smem[98304];
  _Float16* Hs = (_Float16*)smem;
  float* Rs = (float*)(smem + 16512);
  u32t* xl = (u32t*)(smem + 24704);

  const int bid = blockIdx.x;
  const int d = bid & 7;    // domain: rows d*16 .. d*16+15 (one XCD, verified)
  const int s = bid >> 3;   // unit slice: units s*32 .. s*32+31
  const int tid = threadIdx.x;
  const int lane = tid & 63;
  const int wave = tid >> 6;      // 8 waves
  const int p16 = lane & 15;
  const int quad = lane >> 4;
  const int sg = wave & 3;        // unit subgroup (8 units)
  const int kh = wave >> 2;       // 0: exchange + h[0,256) + epilogue
                                  // 1: x-GEMM + h[256,512)

  // ---- one-time XCD-mapping probe ----
  // hwreg(HW_REG_XCC_ID=20, offset=0, size=32) -> imm = (31<<11)|20 = 63508
  if (tid == 0) {
    u32t myx = (u32t)__builtin_amdgcn_s_getreg(63508) & 0xFFu;
    __hip_atomic_store(XccTab + bid, 0x5A5A0000u | myx, __ATOMIC_RELAXED,
                       __HIP_MEMORY_SCOPE_AGENT);
  }
  if (wave == 0) {
    u32t v0, v1;
    for (;;) {
      v0 = __hip_atomic_load(XccTab + lane, __ATOMIC_RELAXED,
                             __HIP_MEMORY_SCOPE_AGENT);
      v1 = __hip_atomic_load(XccTab + 64 + lane, __ATOMIC_RELAXED,
                             __HIP_MEMORY_SCOPE_AGENT);
      if (__all(((v0 >> 16) == 0x5A5Au) & ((v1 >> 16) == 0x5A5Au))) break;
      __builtin_amdgcn_s_sleep(8);
    }
    xl[lane] = v0;
    xl[lane + 64] = v1;
  }
  __syncthreads();
  int fastv;
  {
    const u32t ref = xl[d];
    bool dom = true;
    for (int j = 1; j < 16; ++j) dom = dom && (xl[d + 8 * j] == ref);
    bool sane = false;  // getreg sanity: a constant-reading getreg -> slow
    const u32t z0 = xl[0];
    for (int e = 1; e < 128; ++e) sane = sane || (xl[e] != z0);
    fastv = (dom && sane) ? 1 : 0;
  }
  const bool fastp = (bool)__builtin_amdgcn_readfirstlane(fastv);

  // ---- one-time: gather this wave's B-fragments into VGPRs ----
  // kh0: 16 h-blocks (cols 0..255)   -> b0r[i], kb = 16+i,  i in [0,16)
  // kh1: 16 x-blocks + 16 h-blocks (cols 256..511)
  //      -> b0r[i]: i<16: kb = i (x); i>=16: kb = 16+i (h hi), i in [0,32)
  const int C0 = ((p16 >> 3) & 1) * 512 + s * 32 + sg * 8 + (p16 & 7);  // i/f
  const int C1 = C0 + 1024;                                             // g/o
  half4 b0r[32], b1r[32];
  if (kh == 0) {
#pragma unroll
    for (int i = 0; i < 16; ++i) {
      int kb = 16 + i;
#pragma unroll
      for (int j = 0; j < 4; ++j) {
        int gk = kb * 16 + quad * 4 + j;
        b0r[i][j] = (_Float16)Wh[(size_t)(gk - E_) * 2048 + C0];
        b1r[i][j] = (_Float16)Wh[(size_t)(gk - E_) * 2048 + C1];
      }
    }
  } else {
#pragma unroll
    for (int i = 0; i < 32; ++i) {
      int kb = (i < 16) ? i : (16 + i);
#pragma unroll
      for (int j = 0; j < 4; ++j) {
        int gk = kb * 16 + quad * 4 + j;
        float w0 = (gk < E_) ? Wx[(size_t)gk * 2048 + C0]
                             : Wh[(size_t)(gk - E_) * 2048 + C0];
        float w1 = (gk < E_) ? Wx[(size_t)gk * 2048 + C1]
                             : Wh[(size_t)(gk - E_) * 2048 + C1];
        b0r[i][j] = (_Float16)w0;
        b1r[i][j] = (_Float16)w1;
      }
    }
  }

  const bool lo = (p16 < 8);
  const int uo = p16 & 7;
  const int gu = s * 32 + sg * 8 + uo;               // global unit id
  const float bias0 = bias[(lo ? 0 : 512) + gu];     // i or f
  const float bias1 = bias[(lo ? 1024 : 1536) + gu]; // g or o

  float cst[4] = {0.f, 0.f, 0.f, 0.f};  // c-state (kh0 waves, lo lanes)

  const int brow = d * 16 + p16;   // A-frag batch row
  const int ko = quad * 4;

  for (int t = 0; t < T_; ++t) {
    const int pin = t & 1, pout = pin ^ 1;

    floatx4 acc0 = {0.f, 0.f, 0.f, 0.f};
    floatx4 acc1 = {0.f, 0.f, 0.f, 0.f};

    if (kh == 1) {
      // ---- x-GEMM (kh1 only): 16 K16-blocks ----
      const _Float16* xr = X + ((size_t)t * B_ + brow) * E_ + ko;
#pragma unroll
      for (int i = 0; i < 16; ++i) {
        half4 a = *(const half4*)(xr + i * 16);
        acc0 = MFMA16(a, b0r[i], acc0, 0, 0, 0);
        acc1 = MFMA16(a, b1r[i], acc1, 0, 0, 0);
      }
    } else if (t > 0) {
      // ---- exchange (kh0 only): poll + bulk + stage, overlaps kh1's x ----
      const u32t tgt = (u32t)t;
      u32t v;
      if (fastp) {
        // budget-16 L2-atomic polls (~300cy RMW at the shared XCD-L2),
        // then agent/LLC fallback (proven channel; producer dual-publishes).
        u32t* fa = FlagA + (size_t)(pin * 8 + d) * 16;
        const u32t* fb = FlagB + (size_t)(pin * 8 + d) * 16;
        int budget = 16;
        for (;;) {
          v = (budget > 0)
                  ? poll_l2(fa + p16)
                  : __hip_atomic_load(fb + p16, __ATOMIC_RELAXED,
                                      __HIP_MEMORY_SCOPE_AGENT);
          if (__all(v == tgt)) break;
          --budget;
          __builtin_amdgcn_s_sleep(1);
        }
      } else {
        // unverified mapping: agent/LLC flag only
        const u32t* fb = FlagB + (size_t)(pin * 8 + d) * 16;
        for (;;) {
          v = __hip_atomic_load(fb + p16, __ATOMIC_RELAXED,
                                __HIP_MEMORY_SCOPE_AGENT);
          if (__all(v == tgt)) break;
          __builtin_amdgcn_s_sleep(1);
        }
      }
      const size_t dep = (size_t)(v >> 16);  // always 0; addr dependency

      // bulk: 4 rows/wave (rows wave*4 .. wave*4+3), 8 chunks of 512B
      const _Float16* hq =
          Hq + ((size_t)(pin * 8 + d) * 16 + wave * 4) * 512 + dep;
      u64t hv[8];
      if (fastp) {
        // ONE asm block: 8 pipelined sc0 loads (imm offsets), one vmcnt(0).
        // byte offsets: (j>>1)*1024 + (j&1)*512 relative to base+lane*8 =
        // exactly the slow path's idx=(j>>1)*128+(j&1)*64+lane u64s.
        const u64t* hqb = (const u64t*)hq + lane;
        u64t h0, h1, h2, h3, h4, h5, h6, h7;
        asm volatile(
            "global_load_dwordx2 %0, %8, off sc0\n\t"
            "global_load_dwordx2 %1, %8, off offset:512 sc0\n\t"
            "global_load_dwordx2 %2, %8, off offset:1024 sc0\n\t"
            "global_load_dwordx2 %3, %8, off offset:1536 sc0\n\t"
            "global_load_dwordx2 %4, %8, off offset:2048 sc0\n\t"
            "global_load_dwordx2 %5, %8, off offset:2560 sc0\n\t"
            "global_load_dwordx2 %6, %8, off offset:3072 sc0\n\t"
            "global_load_dwordx2 %7, %8, off offset:3584 sc0\n\t"
            "s_waitcnt vmcnt(0)"
            : "=&v"(h0), "=&v"(h1), "=&v"(h2), "=&v"(h3),
              "=&v"(h4), "=&v"(h5), "=&v"(h6), "=&v"(h7)
            : "v"(hqb)
            : "memory");
        hv[0] = h0; hv[1] = h1; hv[2] = h2; hv[3] = h3;
        hv[4] = h4; hv[5] = h5; hv[6] = h6; hv[7] = h7;
      } else {
#pragma unroll
        for (int j = 0; j < 8; ++j) {
          size_t idx = (size_t)(j >> 1) * 128 + (j & 1) * 64 + lane;
          hv[j] = __hip_atomic_load((const u64t*)hq + idx, __ATOMIC_RELAXED,
                                    __HIP_MEMORY_SCOPE_AGENT);
        }
      }
#pragma unroll
      for (int j = 0; j < 8; ++j) {
        int r = wave * 4 + (j >> 1), half = j & 1;
        *(u64t*)(Hs + r * HROW_ + half * 256 + lane * 4) = hv[j];
      }
    }
    __syncthreads();  // B2: slab ready + x partial-accs in flight

    if (t > 0) {
      // ---- h-GEMM from slab: kh0 -> cols [0,256), kh1 -> [256,512) ----
#pragma unroll
      for (int i = 0; i < 16; ++i) {
        int hk = kh * 16 + i;
        half4 a = *(const half4*)(Hs + p16 * HROW_ + hk * 16 + ko);
        const int wi = (kh == 0) ? i : (16 + i);
        acc0 = MFMA16(a, b0r[wi], acc0, 0, 0, 0);
        acc1 = MFMA16(a, b1r[wi], acc1, 0, 0, 0);
      }
    }

    // ---- kh1 partials -> Rs ----
    if (kh == 1) {
      float* wb = Rs + sg * 512;
      *(floatx4*)(wb + lane * 4) = acc0;
      *(floatx4*)(wb + 256 + lane * 4) = acc1;
    }
    __syncthreads();  // B3: partials ready

    // ---- epilogue (kh0): reduce, gates, fp16 publish ----
    if (kh == 0) {
      const float* rb = Rs + sg * 512;
      floatx4 z0v = acc0 + *(const floatx4*)(rb + lane * 4);
      floatx4 z1v = acc1 + *(const floatx4*)(rb + 256 + lane * 4);
#pragma unroll
      for (int r = 0; r < 4; ++r) {
        float z0 = z0v[r] + bias0;  // i (lo) / f (hi)
        float z1 = z1v[r] + bias1;  // g (lo) / o (hi)
        float s0 = sigmf(z0);
        float s1 = lo ? tanh_f(z1) : sigmf(z1);
        float prod = s0 * s1;                          // i*g on lo lanes
        float fg = __shfl_xor(lo ? prod : s0, 8, 64);  // lo receives f
        float og = __shfl_xor(s1, 8, 64);              // lo receives o
        if (lo) {
          float cn = fg * cst[r] + prod;
          cst[r] = cn;
          float h = og * tanh_f(cn);
          int rowl = quad * 4 + r;                     // local row in domain
          _Float16 hf16 = (_Float16)h;
          unsigned short hb = __builtin_bit_cast(unsigned short, hf16);
          unsigned short* hp =
              (unsigned short*)(Hq +
                                ((size_t)(pout * 8 + d) * 16 + rowl) * 512 + gu);
          if (fastp) {
            // plain store: L1 write-through -> dirty in local XCD-L2;
            // B4 __syncthreads drains vmcnt(0) before the flags go out.
            *hp = hb;
          } else {
            __hip_atomic_store(hp, hb, __ATOMIC_RELAXED,
                               __HIP_MEMORY_SCOPE_AGENT);
          }
        }
      }
    }

    // ---- B4: drain vmcnt(0) for ALL waves (h committed) -> flags ----
    __syncthreads();
    if (tid == 0) {
      size_t fo = (size_t)(pout * 8 + d) * 16 + s;
      if (fastp) {
        // Dual-publish: agent/LLC first (progress guarantee), then the
        // L2-local copy (plain write-through store into the shared L2 —
        // same proven mechanism as the h-data stores).
        __hip_atomic_store(FlagB + fo, (u32t)(t + 1), __ATOMIC_RELAXED,
                           __HIP_MEMORY_SCOPE_AGENT);
        __hip_atomic_store(FlagA + fo, (u32t)(t + 1), __ATOMIC_RELAXED,
                           __HIP_MEMORY_SCOPE_WORKGROUP);
      } else {
        __hip_atomic_store(FlagB + fo, (u32t)(t + 1), __ATOMIC_RELAXED,
                           __HIP_MEMORY_SCOPE_AGENT);
      }
    }
  }
}

// MLP head: one block per batch row. h(512)->relu 128->relu 64->sigmoid 1.
// T=512 even -> final h in Hq parity 0. Kernel boundary orders prior stores
// (end-of-dispatch agent release writes back dirty L2 lines).
__global__ void head_kernel(const _Float16* __restrict__ Hq,
                            const float* __restrict__ W1, const float* __restrict__ b1,
                            const float* __restrict__ W2, const float* __restrict__ b2,
                            const float* __restrict__ W3, const float* __restrict__ b3,
                            float* __restrict__ out) {
  __shared__ float hs[512];
  __shared__ float h1[128];
  __shared__ float h2[64];
  int row = blockIdx.x;
  int tid = threadIdx.x;  // 128 threads
  int dd = row >> 4, rr = row & 15;
  const _Float16* hrow = Hq + ((size_t)dd * 16 + rr) * 512;
  for (int k = tid; k < 512; k += 128) hs[k] = (float)hrow[k];
  __syncthreads();
  float a = b1[tid];
  for (int k = 0; k < 512; ++k) a += hs[k] * W1[k * 128 + tid];
  h1[tid] = fmaxf(a, 0.0f);
  __syncthreads();
  if (tid < 64) {
    float a2 = b2[tid];
    for (int k = 0; k < 128; ++k) a2 += h1[k] * W2[k * 64 + tid];
    h2[tid] = fmaxf(a2, 0.0f);
  }
  __syncthreads();
  if (tid == 0) {
    float a3 = b3[0];
    for (int k = 0; k < 64; ++k) a3 += h2[k] * W3[k];
    out[row] = 1.0f / (1.0f + __expf(-a3));
  }
}

extern "C" void kernel_launch(void* const* d_in, const int* in_sizes, int n_in,
                              void* d_out, int out_size, void* d_ws, size_t ws_size,
                              hipStream_t stream) {
  const int* sent = (const int*)d_in[0];
  const float* emb = (const float*)d_in[1];
  const float* Wx = (const float*)d_in[2];
  const float* Wh = (const float*)d_in[3];
  const float* b = (const float*)d_in[4];
  const float* W1 = (const float*)d_in[5];
  const float* b1 = (const float*)d_in[6];
  const float* W2 = (const float*)d_in[7];
  const float* b2 = (const float*)d_in[8];
  const float* W3 = (const float*)d_in[9];
  const float* b3 = (const float*)d_in[10];
  float* out = (float*)d_out;

  char* ws = (char*)d_ws;
  _Float16* X = (_Float16*)(ws);
  _Float16* Hq = (_Float16*)(ws + (size_t)33554432);
  u32t* FlagA = (u32t*)(ws + (size_t)33554432 + 262144);
  u32t* FlagB = (u32t*)(ws + (size_t)33554432 + 263168);
  u32t* XccTab = (u32t*)(ws + (size_t)33554432 + 264192);

  // Fresh XCD-probe table every launch (graph-capturable stream op).
  hipMemsetAsync(XccTab, 0, 512, stream);
  prep_x_kernel<<<8192, 256, 0, stream>>>(sent, emb, X);
  lstm_kernel<<<NWG_, 512, 0, stream>>>(X, Wx, Wh, b, Hq, FlagA, FlagB, XccTab);
  head_kernel<<<128, 128, 0, stream>>>(Hq, W1, b1, W2, b2, W3, b3, out);
}

// Round 6
// 2589.707 us; speedup vs baseline: 1.3817x; 1.1690x over previous
//
#include <hip/hip_runtime.h>
#include <hip/hip_bf16.h>
#include <hip/hip_fp16.h>

// LSTM_RNN: B=128, T=512, E=256, U=512. R20 = R19 RESUBMITTED (R19 bench
// died to infra: "MI355X container failed twice" — no counters, no kernel
// verdict; the kernel is the proven recombination and cannot deadlock:
// its poll loop is byte-identical to R17/R18's fallback path which passed
// twice).
//   R19/R20 = agent/LLC flag channel (R14-proven) + same-XCD L2 data path
//   (R17/R18-proven). Deletes R17/R18's 16 dead sc0 polls per step.
//   Evidence ledger:
//   - R17/R18 counters: plain h-stores + sc0 pipelined bulk loads are
//     correct (absmax 0) and L2-resident (WRITE 136->3.3MB, FETCH 76->42MB)
//     => keep data path, gated by the XCC probe verdict.
//   - R16 hang + R17/R18 budget-exhaustion (R18 ≡ R17 to 0.4%: LLVM folds
//     fetch_add(p,0) to atomic load -> same sc0 poll): NO L2-local flag
//     channel works on this chip (sc0 store/load visibility). Flag goes
//     through agent/LLC only — the channel R14 ran at 4.57us/step.
//   - Cost model: R18 step 5.75us = R14 4.57 + 2.4 (16 dead polls) - 1.2
//     (data-path gains). R20 removes the 2.4 => predict ~3.3-3.5us/step.
//   Structure (R14-verbatim otherwise): 128 wgs = 8 domains (bid&7, 16
//   rows, XCD-local — PROBE-VERIFIED each launch) x 16 slices (32 units).
//   Producer/consumer wave split: kh1 = x-GEMM + h[256,512); kh0 =
//   exchange + h[0,256) + epilogue. Weights in VGPRs; LDS padded to 96KB
//   -> 1 wg/CU; 3 barriers/step; parity flags + B4/B2 induction (WAR-safe).
// ws layout (~33.82 MiB):
//   X      fp16 [T][B][E]        @ 0          (33,554,432 B)
//   Hq     fp16 [2][8][16][512]  @ 33,554,432 (262,144 B)
//   FlagA  u32  [2][8][16]       @ 33,816,576 (1,024 B)  (unused, reserved)
//   FlagB  u32  [2][8][16]       @ 33,817,600 (1,024 B)  agent/LLC channel
//   XccTab u32  [128]            @ 33,818,624 (512 B)    memset 0/launch

#define B_ 128
#define T_ 512
#define E_ 256
#define U_ 512
#define NWG_ 128
#define HROW_ 516   // Hs row stride (halves)

typedef __attribute__((ext_vector_type(4))) _Float16 half4;
typedef __attribute__((ext_vector_type(4))) float floatx4;
typedef unsigned long long u64t;
typedef unsigned int u32t;

#define MFMA16 __builtin_amdgcn_mfma_f32_16x16x16f16

__device__ __forceinline__ float sigmf(float x) { return 1.0f / (1.0f + __expf(-x)); }
__device__ __forceinline__ float tanh_f(float x) { return 2.0f / (1.0f + __expf(-2.0f * x)) - 1.0f; }

// X[t][b][e] = (fp16) emb[sentence[b][t]][e]; one thread = 8 elements.
__global__ void prep_x_kernel(const int* __restrict__ sent,
                              const float* __restrict__ emb,
                              _Float16* __restrict__ X) {
  int gid = blockIdx.x * blockDim.x + threadIdx.x;  // 2,097,152 total
  int e8 = gid & 31;
  int row = gid >> 5;         // row = t*128 + b
  int b = row & 127;
  int t = row >> 7;
  int word = sent[b * T_ + t];
  const float* src = emb + (size_t)word * E_ + e8 * 8;
  float4 v0 = *(const float4*)(src);
  float4 v1 = *(const float4*)(src + 4);
  _Float16 o[8] = {(_Float16)v0.x, (_Float16)v0.y, (_Float16)v0.z, (_Float16)v0.w,
                   (_Float16)v1.x, (_Float16)v1.y, (_Float16)v1.z, (_Float16)v1.w};
  _Float16* dst = X + (size_t)row * E_ + e8 * 8;
  *(half4*)dst = *(half4*)o;
  *(half4*)(dst + 4) = *(half4*)(o + 4);
}

__global__ __launch_bounds__(512, 1) void lstm_kernel(
    const _Float16* __restrict__ X,
    const float* __restrict__ Wx, const float* __restrict__ Wh,
    const float* __restrict__ bias,
    _Float16* __restrict__ Hq, u32t* FlagA, u32t* FlagB, u32t* XccTab) {
  // LDS: Hs [16][HROW_] fp16 (16,512) | Rs float[4][512] (8,192) |
  // xl u32[128] (512) = 25,216 used; block padded to 96 KB for 1 wg/CU.
  __shared__ __align__(16) char smem[98304];
  _Float16* Hs = (_Float16*)smem;
  float* Rs = (float*)(smem + 16512);
  u32t* xl = (u32t*)(smem + 24704);

  const int bid = blockIdx.x;
  const int d = bid & 7;    // domain: rows d*16 .. d*16+15 (one XCD, verified)
  const int s = bid >> 3;   // unit slice: units s*32 .. s*32+31
  const int tid = threadIdx.x;
  const int lane = tid & 63;
  const int wave = tid >> 6;      // 8 waves
  const int p16 = lane & 15;
  const int quad = lane >> 4;
  const int sg = wave & 3;        // unit subgroup (8 units)
  const int kh = wave >> 2;       // 0: exchange + h[0,256) + epilogue
                                  // 1: x-GEMM + h[256,512)

  // ---- one-time XCD-mapping probe (gates the L2-local DATA path) ----
  // hwreg(HW_REG_XCC_ID=20, offset=0, size=32) -> imm = (31<<11)|20 = 63508
  if (tid == 0) {
    u32t myx = (u32t)__builtin_amdgcn_s_getreg(63508) & 0xFFu;
    __hip_atomic_store(XccTab + bid, 0x5A5A0000u | myx, __ATOMIC_RELAXED,
                       __HIP_MEMORY_SCOPE_AGENT);
  }
  if (wave == 0) {
    u32t v0, v1;
    for (;;) {
      v0 = __hip_atomic_load(XccTab + lane, __ATOMIC_RELAXED,
                             __HIP_MEMORY_SCOPE_AGENT);
      v1 = __hip_atomic_load(XccTab + 64 + lane, __ATOMIC_RELAXED,
                             __HIP_MEMORY_SCOPE_AGENT);
      if (__all(((v0 >> 16) == 0x5A5Au) & ((v1 >> 16) == 0x5A5Au))) break;
      __builtin_amdgcn_s_sleep(8);
    }
    xl[lane] = v0;
    xl[lane + 64] = v1;
  }
  __syncthreads();
  int fastv;
  {
    const u32t ref = xl[d];
    bool dom = true;
    for (int j = 1; j < 16; ++j) dom = dom && (xl[d + 8 * j] == ref);
    bool sane = false;  // getreg sanity: a constant-reading getreg -> slow
    const u32t z0 = xl[0];
    for (int e = 1; e < 128; ++e) sane = sane || (xl[e] != z0);
    fastv = (dom && sane) ? 1 : 0;
  }
  const bool fastp = (bool)__builtin_amdgcn_readfirstlane(fastv);

  // ---- one-time: gather this wave's B-fragments into VGPRs ----
  // kh0: 16 h-blocks (cols 0..255)   -> b0r[i], kb = 16+i,  i in [0,16)
  // kh1: 16 x-blocks + 16 h-blocks (cols 256..511)
  //      -> b0r[i]: i<16: kb = i (x); i>=16: kb = 16+i (h hi), i in [0,32)
  const int C0 = ((p16 >> 3) & 1) * 512 + s * 32 + sg * 8 + (p16 & 7);  // i/f
  const int C1 = C0 + 1024;                                             // g/o
  half4 b0r[32], b1r[32];
  if (kh == 0) {
#pragma unroll
    for (int i = 0; i < 16; ++i) {
      int kb = 16 + i;
#pragma unroll
      for (int j = 0; j < 4; ++j) {
        int gk = kb * 16 + quad * 4 + j;
        b0r[i][j] = (_Float16)Wh[(size_t)(gk - E_) * 2048 + C0];
        b1r[i][j] = (_Float16)Wh[(size_t)(gk - E_) * 2048 + C1];
      }
    }
  } else {
#pragma unroll
    for (int i = 0; i < 32; ++i) {
      int kb = (i < 16) ? i : (16 + i);
#pragma unroll
      for (int j = 0; j < 4; ++j) {
        int gk = kb * 16 + quad * 4 + j;
        float w0 = (gk < E_) ? Wx[(size_t)gk * 2048 + C0]
                             : Wh[(size_t)(gk - E_) * 2048 + C0];
        float w1 = (gk < E_) ? Wx[(size_t)gk * 2048 + C1]
                             : Wh[(size_t)(gk - E_) * 2048 + C1];
        b0r[i][j] = (_Float16)w0;
        b1r[i][j] = (_Float16)w1;
      }
    }
  }

  const bool lo = (p16 < 8);
  const int uo = p16 & 7;
  const int gu = s * 32 + sg * 8 + uo;               // global unit id
  const float bias0 = bias[(lo ? 0 : 512) + gu];     // i or f
  const float bias1 = bias[(lo ? 1024 : 1536) + gu]; // g or o

  float cst[4] = {0.f, 0.f, 0.f, 0.f};  // c-state (kh0 waves, lo lanes)

  const int brow = d * 16 + p16;   // A-frag batch row
  const int ko = quad * 4;

  for (int t = 0; t < T_; ++t) {
    const int pin = t & 1, pout = pin ^ 1;

    floatx4 acc0 = {0.f, 0.f, 0.f, 0.f};
    floatx4 acc1 = {0.f, 0.f, 0.f, 0.f};

    if (kh == 1) {
      // ---- x-GEMM (kh1 only): 16 K16-blocks ----
      const _Float16* xr = X + ((size_t)t * B_ + brow) * E_ + ko;
#pragma unroll
      for (int i = 0; i < 16; ++i) {
        half4 a = *(const half4*)(xr + i * 16);
        acc0 = MFMA16(a, b0r[i], acc0, 0, 0, 0);
        acc1 = MFMA16(a, b1r[i], acc1, 0, 0, 0);
      }
    } else if (t > 0) {
      // ---- exchange (kh0 only): poll + bulk + stage, overlaps kh1's x ----
      // Flag: agent/LLC ONLY (proven channel; all L2-local flag attempts
      // failed R16-R18). Data: sc0/L2 under the same-XCD verdict (proven).
      const u32t tgt = (u32t)t;
      u32t v;
      {
        const u32t* fb = FlagB + (size_t)(pin * 8 + d) * 16;
        for (;;) {
          v = __hip_atomic_load(fb + p16, __ATOMIC_RELAXED,
                                __HIP_MEMORY_SCOPE_AGENT);
          if (__all(v == tgt)) break;
          __builtin_amdgcn_s_sleep(1);
        }
      }
      const size_t dep = (size_t)(v >> 16);  // always 0; addr dependency

      // bulk: 4 rows/wave (rows wave*4 .. wave*4+3), 8 chunks of 512B
      const _Float16* hq =
          Hq + ((size_t)(pin * 8 + d) * 16 + wave * 4) * 512 + dep;
      u64t hv[8];
      if (fastp) {
        // ONE asm block: 8 pipelined sc0 loads (imm offsets), one vmcnt(0).
        // byte offsets: (j>>1)*1024 + (j&1)*512 relative to base+lane*8 =
        // exactly the slow path's idx=(j>>1)*128+(j&1)*64+lane u64s.
        const u64t* hqb = (const u64t*)hq + lane;
        u64t h0, h1, h2, h3, h4, h5, h6, h7;
        asm volatile(
            "global_load_dwordx2 %0, %8, off sc0\n\t"
            "global_load_dwordx2 %1, %8, off offset:512 sc0\n\t"
            "global_load_dwordx2 %2, %8, off offset:1024 sc0\n\t"
            "global_load_dwordx2 %3, %8, off offset:1536 sc0\n\t"
            "global_load_dwordx2 %4, %8, off offset:2048 sc0\n\t"
            "global_load_dwordx2 %5, %8, off offset:2560 sc0\n\t"
            "global_load_dwordx2 %6, %8, off offset:3072 sc0\n\t"
            "global_load_dwordx2 %7, %8, off offset:3584 sc0\n\t"
            "s_waitcnt vmcnt(0)"
            : "=&v"(h0), "=&v"(h1), "=&v"(h2), "=&v"(h3),
              "=&v"(h4), "=&v"(h5), "=&v"(h6), "=&v"(h7)
            : "v"(hqb)
            : "memory");
        hv[0] = h0; hv[1] = h1; hv[2] = h2; hv[3] = h3;
        hv[4] = h4; hv[5] = h5; hv[6] = h6; hv[7] = h7;
      } else {
#pragma unroll
        for (int j = 0; j < 8; ++j) {
          size_t idx = (size_t)(j >> 1) * 128 + (j & 1) * 64 + lane;
          hv[j] = __hip_atomic_load((const u64t*)hq + idx, __ATOMIC_RELAXED,
                                    __HIP_MEMORY_SCOPE_AGENT);
        }
      }
#pragma unroll
      for (int j = 0; j < 8; ++j) {
        int r = wave * 4 + (j >> 1), half = j & 1;
        *(u64t*)(Hs + r * HROW_ + half * 256 + lane * 4) = hv[j];
      }
    }
    __syncthreads();  // B2: slab ready + x partial-accs in flight

    if (t > 0) {
      // ---- h-GEMM from slab: kh0 -> cols [0,256), kh1 -> [256,512) ----
#pragma unroll
      for (int i = 0; i < 16; ++i) {
        int hk = kh * 16 + i;
        half4 a = *(const half4*)(Hs + p16 * HROW_ + hk * 16 + ko);
        const int wi = (kh == 0) ? i : (16 + i);
        acc0 = MFMA16(a, b0r[wi], acc0, 0, 0, 0);
        acc1 = MFMA16(a, b1r[wi], acc1, 0, 0, 0);
      }
    }

    // ---- kh1 partials -> Rs ----
    if (kh == 1) {
      float* wb = Rs + sg * 512;
      *(floatx4*)(wb + lane * 4) = acc0;
      *(floatx4*)(wb + 256 + lane * 4) = acc1;
    }
    __syncthreads();  // B3: partials ready

    // ---- epilogue (kh0): reduce, gates, fp16 publish ----
    if (kh == 0) {
      const float* rb = Rs + sg * 512;
      floatx4 z0v = acc0 + *(const floatx4*)(rb + lane * 4);
      floatx4 z1v = acc1 + *(const floatx4*)(rb + 256 + lane * 4);
#pragma unroll
      for (int r = 0; r < 4; ++r) {
        float z0 = z0v[r] + bias0;  // i (lo) / f (hi)
        float z1 = z1v[r] + bias1;  // g (lo) / o (hi)
        float s0 = sigmf(z0);
        float s1 = lo ? tanh_f(z1) : sigmf(z1);
        float prod = s0 * s1;                          // i*g on lo lanes
        float fg = __shfl_xor(lo ? prod : s0, 8, 64);  // lo receives f
        float og = __shfl_xor(s1, 8, 64);              // lo receives o
        if (lo) {
          float cn = fg * cst[r] + prod;
          cst[r] = cn;
          float h = og * tanh_f(cn);
          int rowl = quad * 4 + r;                     // local row in domain
          _Float16 hf16 = (_Float16)h;
          unsigned short hb = __builtin_bit_cast(unsigned short, hf16);
          unsigned short* hp =
              (unsigned short*)(Hq +
                                ((size_t)(pout * 8 + d) * 16 + rowl) * 512 + gu);
          if (fastp) {
            // plain store: L1 write-through -> dirty in local XCD-L2;
            // B4 __syncthreads drains vmcnt(0) before the flag goes out.
            *hp = hb;
          } else {
            __hip_atomic_store(hp, hb, __ATOMIC_RELAXED,
                               __HIP_MEMORY_SCOPE_AGENT);
          }
        }
      }
    }

    // ---- B4: drain vmcnt(0) for ALL waves (h committed) -> flag ----
    __syncthreads();
    if (tid == 0) {
      size_t fo = (size_t)(pout * 8 + d) * 16 + s;
      __hip_atomic_store(FlagB + fo, (u32t)(t + 1), __ATOMIC_RELAXED,
                         __HIP_MEMORY_SCOPE_AGENT);    // LLC, fire-and-forget
    }
  }
}

// MLP head: one block per batch row. h(512)->relu 128->relu 64->sigmoid 1.
// T=512 even -> final h in Hq parity 0. Kernel boundary orders prior stores
// (end-of-dispatch agent release writes back dirty L2 lines).
__global__ void head_kernel(const _Float16* __restrict__ Hq,
                            const float* __restrict__ W1, const float* __restrict__ b1,
                            const float* __restrict__ W2, const float* __restrict__ b2,
                            const float* __restrict__ W3, const float* __restrict__ b3,
                            float* __restrict__ out) {
  __shared__ float hs[512];
  __shared__ float h1[128];
  __shared__ float h2[64];
  int row = blockIdx.x;
  int tid = threadIdx.x;  // 128 threads
  int dd = row >> 4, rr = row & 15;
  const _Float16* hrow = Hq + ((size_t)dd * 16 + rr) * 512;
  for (int k = tid; k < 512; k += 128) hs[k] = (float)hrow[k];
  __syncthreads();
  float a = b1[tid];
  for (int k = 0; k < 512; ++k) a += hs[k] * W1[k * 128 + tid];
  h1[tid] = fmaxf(a, 0.0f);
  __syncthreads();
  if (tid < 64) {
    float a2 = b2[tid];
    for (int k = 0; k < 128; ++k) a2 += h1[k] * W2[k * 64 + tid];
    h2[tid] = fmaxf(a2, 0.0f);
  }
  __syncthreads();
  if (tid == 0) {
    float a3 = b3[0];
    for (int k = 0; k < 64; ++k) a3 += h2[k] * W3[k];
    out[row] = 1.0f / (1.0f + __expf(-a3));
  }
}

extern "C" void kernel_launch(void* const* d_in, const int* in_sizes, int n_in,
                              void* d_out, int out_size, void* d_ws, size_t ws_size,
                              hipStream_t stream) {
  const int* sent = (const int*)d_in[0];
  const float* emb = (const float*)d_in[1];
  const float* Wx = (const float*)d_in[2];
  const float* Wh = (const float*)d_in[3];
  const float* b = (const float*)d_in[4];
  const float* W1 = (const float*)d_in[5];
  const float* b1 = (const float*)d_in[6];
  const float* W2 = (const float*)d_in[7];
  const float* b2 = (const float*)d_in[8];
  const float* W3 = (const float*)d_in[9];
  const float* b3 = (const float*)d_in[10];
  float* out = (float*)d_out;

  char* ws = (char*)d_ws;
  _Float16* X = (_Float16*)(ws);
  _Float16* Hq = (_Float16*)(ws + (size_t)33554432);
  u32t* FlagA = (u32t*)(ws + (size_t)33554432 + 262144);
  u32t* FlagB = (u32t*)(ws + (size_t)33554432 + 263168);
  u32t* XccTab = (u32t*)(ws + (size_t)33554432 + 264192);

  // Fresh XCD-probe table every launch (graph-capturable stream op).
  hipMemsetAsync(XccTab, 0, 512, stream);
  prep_x_kernel<<<8192, 256, 0, stream>>>(sent, emb, X);
  lstm_kernel<<<NWG_, 512, 0, stream>>>(X, Wx, Wh, b, Hq, FlagA, FlagB, XccTab);
  head_kernel<<<128, 128, 0, stream>>>(Hq, W1, b1, W2, b2, W3, b3, out);
}

// Round 7
// 2234.743 us; speedup vs baseline: 1.6012x; 1.1588x over previous
//
#include <hip/hip_runtime.h>
#include <hip/hip_bf16.h>
#include <hip/hip_fp16.h>

// LSTM_RNN: B=128, T=512, E=256, U=512. R21 = R20 + ATOMIC-RMW L2 FLAG
// CHANNEL (the one mechanism not yet probed).
//   R20 post-mortem: removing R18's 16 dead polls saved only 0.68us/step
//   (not 2.4) -> the exchange is bound by flag publish->observe latency
//   (~2-2.5us/step, ~50% of runtime), not poll count. All three failed
//   L2-flag probes (R16 hang, R17/R18 budget-exhaust) polled with an sc0
//   PLAIN LOAD (R18's fetch_add(p,0) folded to a load: timing == R17 to
//   0.1%). Untested: real atomic RMW on BOTH halves, which executes AT the
//   owning cache instead of reading through stale lines:
//     * publish: asm global_atomic_swap (plain scope -> XCD-L2 on
//       MI300-family; sc1 is what escalates to LLC), issued FIRST at B4.
//     * poll: asm global_atomic_add dst,addr,0,sc0 (returns old) — an RMW
//       cannot be served by a stale clean line.
//   Two-sided safety: if plain atomics actually execute at LLC, BOTH
//   halves land at LLC -> channel still works at agent speed (no loss).
//   Mismatch needs cross-XCD, excluded by the probe verdict; budget-6
//   fallback to FlagB (agent, proven) caps even that. Hang-proof.
//   Contention: only WAVE 0 polls (16 lanes, 16 words; 16 RMW/word/round
//   per domain); waves 1-3 gate on an LDS 'go' word wave0 releases.
//   Flags+XccTab memset-0 each launch (kills first-launch garbage hazard).
//   Data path R17-R20-proven (absmax<=2^-8, WRITE 3.3MB, FETCH 42MB):
//   plain write-through h stores (L2 dirty), ONE asm block of 8 pipelined
//   sc0 bulk loads + single vmcnt(0), gated on the same-XCD verdict.
// ws layout (~33.82 MiB):
//   X      fp16 [T][B][E]        @ 0          (33,554,432 B)
//   Hq     fp16 [2][8][16][512]  @ 33,554,432 (262,144 B)
//   FlagA  u32  [2][8][16]       @ 33,816,576 (1,024 B)  atomic/L2 channel
//   FlagB  u32  [2][8][16]       @ 33,817,600 (1,024 B)  agent/LLC channel
//   XccTab u32  [128]            @ 33,818,624 (512 B)
//   (FlagA..XccTab = 2,560 B contiguous, memset 0 each launch)

#define B_ 128
#define T_ 512
#define E_ 256
#define U_ 512
#define NWG_ 128
#define HROW_ 516   // Hs row stride (halves)

typedef __attribute__((ext_vector_type(4))) _Float16 half4;
typedef __attribute__((ext_vector_type(4))) float floatx4;
typedef unsigned long long u64t;
typedef unsigned int u32t;

#define MFMA16 __builtin_amdgcn_mfma_f32_16x16x16f16

__device__ __forceinline__ float sigmf(float x) { return 1.0f / (1.0f + __expf(-x)); }
__device__ __forceinline__ float tanh_f(float x) { return 2.0f / (1.0f + __expf(-2.0f * x)) - 1.0f; }

// X[t][b][e] = (fp16) emb[sentence[b][t]][e]; one thread = 8 elements.
__global__ void prep_x_kernel(const int* __restrict__ sent,
                              const float* __restrict__ emb,
                              _Float16* __restrict__ X) {
  int gid = blockIdx.x * blockDim.x + threadIdx.x;  // 2,097,152 total
  int e8 = gid & 31;
  int row = gid >> 5;         // row = t*128 + b
  int b = row & 127;
  int t = row >> 7;
  int word = sent[b * T_ + t];
  const float* src = emb + (size_t)word * E_ + e8 * 8;
  float4 v0 = *(const float4*)(src);
  float4 v1 = *(const float4*)(src + 4);
  _Float16 o[8] = {(_Float16)v0.x, (_Float16)v0.y, (_Float16)v0.z, (_Float16)v0.w,
                   (_Float16)v1.x, (_Float16)v1.y, (_Float16)v1.z, (_Float16)v1.w};
  _Float16* dst = X + (size_t)row * E_ + e8 * 8;
  *(half4*)dst = *(half4*)o;
  *(half4*)(dst + 4) = *(half4*)(o + 4);
}

__global__ __launch_bounds__(512, 1) void lstm_kernel(
    const _Float16* __restrict__ X,
    const float* __restrict__ Wx, const float* __restrict__ Wh,
    const float* __restrict__ bias,
    _Float16* __restrict__ Hq, u32t* FlagA, u32t* FlagB, u32t* XccTab) {
  // LDS: Hs [16][HROW_] fp16 (16,512) | Rs float[4][512] (8,192) |
  // xl u32[128] (512) | go u32 (4) = 25,220 used; padded to 96 KB -> 1 wg/CU.
  __shared__ __align__(16) char smem[98304];
  _Float16* Hs = (_Float16*)smem;
  float* Rs = (float*)(smem + 16512);
  u32t* xl = (u32t*)(smem + 24704);
  volatile u32t* goP = (volatile u32t*)(smem + 25216);

  const int bid = blockIdx.x;
  const int d = bid & 7;    // domain: rows d*16 .. d*16+15 (one XCD, verified)
  const int s = bid >> 3;   // unit slice: units s*32 .. s*32+31
  const int tid = threadIdx.x;
  const int lane = tid & 63;
  const int wave = tid >> 6;      // 8 waves
  const int p16 = lane & 15;
  const int quad = lane >> 4;
  const int sg = wave & 3;        // unit subgroup (8 units)
  const int kh = wave >> 2;       // 0: exchange + h[0,256) + epilogue
                                  // 1: x-GEMM + h[256,512)

  // ---- one-time XCD-mapping probe (gates the L2-local DATA path) ----
  // hwreg(HW_REG_XCC_ID=20, offset=0, size=32) -> imm = (31<<11)|20 = 63508
  if (tid == 0) {
    *goP = 0u;
    u32t myx = (u32t)__builtin_amdgcn_s_getreg(63508) & 0xFFu;
    __hip_atomic_store(XccTab + bid, 0x5A5A0000u | myx, __ATOMIC_RELAXED,
                       __HIP_MEMORY_SCOPE_AGENT);
  }
  if (wave == 0) {
    u32t v0, v1;
    for (;;) {
      v0 = __hip_atomic_load(XccTab + lane, __ATOMIC_RELAXED,
                             __HIP_MEMORY_SCOPE_AGENT);
      v1 = __hip_atomic_load(XccTab + 64 + lane, __ATOMIC_RELAXED,
                             __HIP_MEMORY_SCOPE_AGENT);
      if (__all(((v0 >> 16) == 0x5A5Au) & ((v1 >> 16) == 0x5A5Au))) break;
      __builtin_amdgcn_s_sleep(8);
    }
    xl[lane] = v0;
    xl[lane + 64] = v1;
  }
  __syncthreads();
  int fastv;
  {
    const u32t ref = xl[d];
    bool dom = true;
    for (int j = 1; j < 16; ++j) dom = dom && (xl[d + 8 * j] == ref);
    bool sane = false;  // getreg sanity: a constant-reading getreg -> slow
    const u32t z0 = xl[0];
    for (int e = 1; e < 128; ++e) sane = sane || (xl[e] != z0);
    fastv = (dom && sane) ? 1 : 0;
  }
  const bool fastp = (bool)__builtin_amdgcn_readfirstlane(fastv);

  // ---- one-time: gather this wave's B-fragments into VGPRs ----
  // kh0: 16 h-blocks (cols 0..255)   -> b0r[i], kb = 16+i,  i in [0,16)
  // kh1: 16 x-blocks + 16 h-blocks (cols 256..511)
  //      -> b0r[i]: i<16: kb = i (x); i>=16: kb = 16+i (h hi), i in [0,32)
  const int C0 = ((p16 >> 3) & 1) * 512 + s * 32 + sg * 8 + (p16 & 7);  // i/f
  const int C1 = C0 + 1024;                                             // g/o
  half4 b0r[32], b1r[32];
  if (kh == 0) {
#pragma unroll
    for (int i = 0; i < 16; ++i) {
      int kb = 16 + i;
#pragma unroll
      for (int j = 0; j < 4; ++j) {
        int gk = kb * 16 + quad * 4 + j;
        b0r[i][j] = (_Float16)Wh[(size_t)(gk - E_) * 2048 + C0];
        b1r[i][j] = (_Float16)Wh[(size_t)(gk - E_) * 2048 + C1];
      }
    }
  } else {
#pragma unroll
    for (int i = 0; i < 32; ++i) {
      int kb = (i < 16) ? i : (16 + i);
#pragma unroll
      for (int j = 0; j < 4; ++j) {
        int gk = kb * 16 + quad * 4 + j;
        float w0 = (gk < E_) ? Wx[(size_t)gk * 2048 + C0]
                             : Wh[(size_t)(gk - E_) * 2048 + C0];
        float w1 = (gk < E_) ? Wx[(size_t)gk * 2048 + C1]
                             : Wh[(size_t)(gk - E_) * 2048 + C1];
        b0r[i][j] = (_Float16)w0;
        b1r[i][j] = (_Float16)w1;
      }
    }
  }

  const bool lo = (p16 < 8);
  const int uo = p16 & 7;
  const int gu = s * 32 + sg * 8 + uo;               // global unit id
  const float bias0 = bias[(lo ? 0 : 512) + gu];     // i or f
  const float bias1 = bias[(lo ? 1024 : 1536) + gu]; // g or o

  float cst[4] = {0.f, 0.f, 0.f, 0.f};  // c-state (kh0 waves, lo lanes)

  const int brow = d * 16 + p16;   // A-frag batch row
  const int ko = quad * 4;

  for (int t = 0; t < T_; ++t) {
    const int pin = t & 1, pout = pin ^ 1;

    floatx4 acc0 = {0.f, 0.f, 0.f, 0.f};
    floatx4 acc1 = {0.f, 0.f, 0.f, 0.f};

    u32t gv = (u32t)t;  // gate value; ==t after the exchange gate passes

    if (kh == 1) {
      // ---- x-GEMM (kh1 only): 16 K16-blocks ----
      const _Float16* xr = X + ((size_t)t * B_ + brow) * E_ + ko;
#pragma unroll
      for (int i = 0; i < 16; ++i) {
        half4 a = *(const half4*)(xr + i * 16);
        acc0 = MFMA16(a, b0r[i], acc0, 0, 0, 0);
        acc1 = MFMA16(a, b1r[i], acc1, 0, 0, 0);
      }
    } else if (t > 0) {
      // ---- exchange (kh0 only): gate + bulk + stage, overlaps kh1's x ----
      const u32t tgt = (u32t)t;
      if (wave == 0) {
        // wave 0 is the sole poller (16 lanes, 16 distinct flag words).
        u32t v;
        if (fastp) {
          u32t* fa = FlagA + (size_t)(pin * 8 + d) * 16;
          const u32t* fb = FlagB + (size_t)(pin * 8 + d) * 16;
          int budget = 6;
          for (;;) {
            if (budget > 0) {
              // atomic RMW add-0 sc0: executes at the owning cache,
              // returns the authoritative current value.
              u32t old = tgt;
              if (lane < 16) {
                u32t* ap = fa + lane;
                asm volatile(
                    "global_atomic_add %0, %1, %2, off sc0\n\t"
                    "s_waitcnt vmcnt(0)"
                    : "=&v"(old) : "v"(ap), "v"(0u) : "memory");
              }
              v = old;
            } else {
              v = (lane < 16)
                      ? __hip_atomic_load(fb + lane, __ATOMIC_RELAXED,
                                          __HIP_MEMORY_SCOPE_AGENT)
                      : tgt;
            }
            if (__all(v == tgt)) break;
            --budget;
            if (budget < 4) __builtin_amdgcn_s_sleep(1);
          }
        } else {
          const u32t* fb = FlagB + (size_t)(pin * 8 + d) * 16;
          for (;;) {
            v = (lane < 16)
                    ? __hip_atomic_load(fb + lane, __ATOMIC_RELAXED,
                                        __HIP_MEMORY_SCOPE_AGENT)
                    : tgt;
            if (__all(v == tgt)) break;
            __builtin_amdgcn_s_sleep(1);
          }
        }
        gv = v;             // == tgt on every lane
        if (lane == 0) *goP = tgt;   // LDS release for waves 1-3
      } else {
        // waves 1-3: LDS gate (wave0 wrote go=t after data-safe flag).
        u32t g;
        do { g = *goP; } while (g < tgt);
        gv = g;             // == tgt (same-WG barriers bound the step)
      }
      const size_t dep = (size_t)(gv >> 16);  // always 0; addr dependency

      // bulk: 4 rows/wave (rows wave*4 .. wave*4+3), 8 chunks of 512B
      const _Float16* hq =
          Hq + ((size_t)(pin * 8 + d) * 16 + wave * 4) * 512 + dep;
      u64t hv[8];
      if (fastp) {
        // ONE asm block: 8 pipelined sc0 loads (imm offsets), one vmcnt(0).
        const u64t* hqb = (const u64t*)hq + lane;
        u64t h0, h1, h2, h3, h4, h5, h6, h7;
        asm volatile(
            "global_load_dwordx2 %0, %8, off sc0\n\t"
            "global_load_dwordx2 %1, %8, off offset:512 sc0\n\t"
            "global_load_dwordx2 %2, %8, off offset:1024 sc0\n\t"
            "global_load_dwordx2 %3, %8, off offset:1536 sc0\n\t"
            "global_load_dwordx2 %4, %8, off offset:2048 sc0\n\t"
            "global_load_dwordx2 %5, %8, off offset:2560 sc0\n\t"
            "global_load_dwordx2 %6, %8, off offset:3072 sc0\n\t"
            "global_load_dwordx2 %7, %8, off offset:3584 sc0\n\t"
            "s_waitcnt vmcnt(0)"
            : "=&v"(h0), "=&v"(h1), "=&v"(h2), "=&v"(h3),
              "=&v"(h4), "=&v"(h5), "=&v"(h6), "=&v"(h7)
            : "v"(hqb)
            : "memory");
        hv[0] = h0; hv[1] = h1; hv[2] = h2; hv[3] = h3;
        hv[4] = h4; hv[5] = h5; hv[6] = h6; hv[7] = h7;
      } else {
#pragma unroll
        for (int j = 0; j < 8; ++j) {
          size_t idx = (size_t)(j >> 1) * 128 + (j & 1) * 64 + lane;
          hv[j] = __hip_atomic_load((const u64t*)hq + idx, __ATOMIC_RELAXED,
                                    __HIP_MEMORY_SCOPE_AGENT);
        }
      }
#pragma unroll
      for (int j = 0; j < 8; ++j) {
        int r = wave * 4 + (j >> 1), half = j & 1;
        *(u64t*)(Hs + r * HROW_ + half * 256 + lane * 4) = hv[j];
      }
    }
    __syncthreads();  // B2: slab ready + x partial-accs in flight

    if (t > 0) {
      // ---- h-GEMM from slab: kh0 -> cols [0,256), kh1 -> [256,512) ----
#pragma unroll
      for (int i = 0; i < 16; ++i) {
        int hk = kh * 16 + i;
        half4 a = *(const half4*)(Hs + p16 * HROW_ + hk * 16 + ko);
        const int wi = (kh == 0) ? i : (16 + i);
        acc0 = MFMA16(a, b0r[wi], acc0, 0, 0, 0);
        acc1 = MFMA16(a, b1r[wi], acc1, 0, 0, 0);
      }
    }

    // ---- kh1 partials -> Rs ----
    if (kh == 1) {
      float* wb = Rs + sg * 512;
      *(floatx4*)(wb + lane * 4) = acc0;
      *(floatx4*)(wb + 256 + lane * 4) = acc1;
    }
    __syncthreads();  // B3: partials ready

    // ---- epilogue (kh0): reduce, gates, fp16 publish ----
    if (kh == 0) {
      const float* rb = Rs + sg * 512;
      floatx4 z0v = acc0 + *(const floatx4*)(rb + lane * 4);
      floatx4 z1v = acc1 + *(const floatx4*)(rb + 256 + lane * 4);
#pragma unroll
      for (int r = 0; r < 4; ++r) {
        float z0 = z0v[r] + bias0;  // i (lo) / f (hi)
        float z1 = z1v[r] + bias1;  // g (lo) / o (hi)
        float s0 = sigmf(z0);
        float s1 = lo ? tanh_f(z1) : sigmf(z1);
        float prod = s0 * s1;                          // i*g on lo lanes
        float fg = __shfl_xor(lo ? prod : s0, 8, 64);  // lo receives f
        float og = __shfl_xor(s1, 8, 64);              // lo receives o
        if (lo) {
          float cn = fg * cst[r] + prod;
          cst[r] = cn;
          float h = og * tanh_f(cn);
          int rowl = quad * 4 + r;                     // local row in domain
          _Float16 hf16 = (_Float16)h;
          unsigned short hb = __builtin_bit_cast(unsigned short, hf16);
          unsigned short* hp =
              (unsigned short*)(Hq +
                                ((size_t)(pout * 8 + d) * 16 + rowl) * 512 + gu);
          if (fastp) {
            // plain store: L1 write-through -> dirty in local XCD-L2;
            // B4 __syncthreads drains vmcnt(0) before the flags go out.
            *hp = hb;
          } else {
            __hip_atomic_store(hp, hb, __ATOMIC_RELAXED,
                               __HIP_MEMORY_SCOPE_AGENT);
          }
        }
      }
    }

    // ---- B4: drain vmcnt(0) for ALL waves (h committed) -> flags ----
    __syncthreads();
    if (tid == 0) {
      size_t fo = (size_t)(pout * 8 + d) * 16 + s;
      if (fastp) {
        // Fast channel first: atomic swap executes at the owning cache
        // (same cache the consumer's RMW poll reads — scope bits match).
        u32t* ap = FlagA + fo;
        u32t nv = (u32t)(t + 1);
        asm volatile("global_atomic_swap %0, %1, off"
                     :: "v"(ap), "v"(nv) : "memory");
      }
      __hip_atomic_store(FlagB + fo, (u32t)(t + 1), __ATOMIC_RELAXED,
                         __HIP_MEMORY_SCOPE_AGENT);    // progress guarantee
    }
  }
}

// MLP head: one block per batch row. h(512)->relu 128->relu 64->sigmoid 1.
// T=512 even -> final h in Hq parity 0. Kernel boundary orders prior stores
// (end-of-dispatch agent release writes back dirty L2 lines).
__global__ void head_kernel(const _Float16* __restrict__ Hq,
                            const float* __restrict__ W1, const float* __restrict__ b1,
                            const float* __restrict__ W2, const float* __restrict__ b2,
                            const float* __restrict__ W3, const float* __restrict__ b3,
                            float* __restrict__ out) {
  __shared__ float hs[512];
  __shared__ float h1[128];
  __shared__ float h2[64];
  int row = blockIdx.x;
  int tid = threadIdx.x;  // 128 threads
  int dd = row >> 4, rr = row & 15;
  const _Float16* hrow = Hq + ((size_t)dd * 16 + rr) * 512;
  for (int k = tid; k < 512; k += 128) hs[k] = (float)hrow[k];
  __syncthreads();
  float a = b1[tid];
  for (int k = 0; k < 512; ++k) a += hs[k] * W1[k * 128 + tid];
  h1[tid] = fmaxf(a, 0.0f);
  __syncthreads();
  if (tid < 64) {
    float a2 = b2[tid];
    for (int k = 0; k < 128; ++k) a2 += h1[k] * W2[k * 64 + tid];
    h2[tid] = fmaxf(a2, 0.0f);
  }
  __syncthreads();
  if (tid == 0) {
    float a3 = b3[0];
    for (int k = 0; k < 64; ++k) a3 += h2[k] * W3[k];
    out[row] = 1.0f / (1.0f + __expf(-a3));
  }
}

extern "C" void kernel_launch(void* const* d_in, const int* in_sizes, int n_in,
                              void* d_out, int out_size, void* d_ws, size_t ws_size,
                              hipStream_t stream) {
  const int* sent = (const int*)d_in[0];
  const float* emb = (const float*)d_in[1];
  const float* Wx = (const float*)d_in[2];
  const float* Wh = (const float*)d_in[3];
  const float* b = (const float*)d_in[4];
  const float* W1 = (const float*)d_in[5];
  const float* b1 = (const float*)d_in[6];
  const float* W2 = (const float*)d_in[7];
  const float* b2 = (const float*)d_in[8];
  const float* W3 = (const float*)d_in[9];
  const float* b3 = (const float*)d_in[10];
  float* out = (float*)d_out;

  char* ws = (char*)d_ws;
  _Float16* X = (_Float16*)(ws);
  _Float16* Hq = (_Float16*)(ws + (size_t)33554432);
  u32t* FlagA = (u32t*)(ws + (size_t)33554432 + 262144);
  u32t* FlagB = (u32t*)(ws + (size_t)33554432 + 263168);
  u32t* XccTab = (u32t*)(ws + (size_t)33554432 + 264192);

  // Zero FlagA+FlagB+XccTab (contiguous 2,560 B) every launch:
  // removes the first-launch garbage hazard; 0 never matches t in [1,512].
  hipMemsetAsync(FlagA, 0, 2560, stream);
  prep_x_kernel<<<8192, 256, 0, stream>>>(sent, emb, X);
  lstm_kernel<<<NWG_, 512, 0, stream>>>(X, Wx, Wh, b, Hq, FlagA, FlagB, XccTab);
  head_kernel<<<128, 128, 0, stream>>>(Hq, W1, b1, W2, b2, W3, b3, out);
}

// Round 8
// 1848.308 us; speedup vs baseline: 1.9359x; 1.2091x over previous
//
#include <hip/hip_runtime.h>
#include <hip/hip_bf16.h>
#include <hip/hip_fp16.h>

// LSTM_RNN: B=128, T=512, E=256, U=512. R22 = R21 − B4: producer-side
// publish via per-wave drain + LDS counter (kh1 waves free-run into the
// next x-GEMM).
//   R21 results (session best, 2149us steady): atomic-RMW L2 flag channel
//   WORKS (WRITE_SIZE +8.5MB = RMW writeback signature; absmax 0; -0.87
//   us/step vs R20). Remaining step 4.2us >> modeled 2-2.5us serial chain;
//   residual = epilogue/publish tail serialized behind B4 (kh1 idle from
//   B3 to B4) + max-of-16 producer jitter.
//   - NEW: B4 deleted. Ordering "all kh0 h-stores drained before flag" is
//     now: each kh0 wave s_waitcnt vmcnt(0) -> LDS atomicAdd; the 4th
//     arrival (old==4t+3) publishes FlagA (atomic swap, L2) + FlagB
//     (agent, progress guarantee). LDS dependency chains publish after
//     all drains — same ordering B4 gave, without blocking kh1.
//   - kh1 now runs B3(t) -> x-GEMM(t+1) directly: the ~800-1500cy
//     epilogue+drain+publish tail overlaps next-step compute. 2 barriers/
//     step (B2, B3).
//   - WAR safety unchanged: Rs(t+1) written after B2(t+1) which kh0
//     reaches only after epilogue(t); Hs staged(t+1) after B3(t); flag
//     slot reuse protected by parity + equality-poll induction (publish
//     of t+1 still strictly after the WG's own step-t gate).
//   - Everything else R21-verbatim: XCC probe gating sc0 data path
//     (WRITE 3.3->11.8MB only from atomics; h stores plain write-through,
//     bulk = ONE asm block of 8 pipelined sc0 loads), wave0-only RMW poll
//     (budget 6) + agent fallback, LDS go release, memset-0 flags.
// ws layout (~33.82 MiB):
//   X      fp16 [T][B][E]        @ 0          (33,554,432 B)
//   Hq     fp16 [2][8][16][512]  @ 33,554,432 (262,144 B)
//   FlagA  u32  [2][8][16]       @ 33,816,576 (1,024 B)  atomic/L2 channel
//   FlagB  u32  [2][8][16]       @ 33,817,600 (1,024 B)  agent/LLC channel
//   XccTab u32  [128]            @ 33,818,624 (512 B)
//   (FlagA..XccTab = 2,560 B contiguous, memset 0 each launch)

#define B_ 128
#define T_ 512
#define E_ 256
#define U_ 512
#define NWG_ 128
#define HROW_ 516   // Hs row stride (halves)

typedef __attribute__((ext_vector_type(4))) _Float16 half4;
typedef __attribute__((ext_vector_type(4))) float floatx4;
typedef unsigned long long u64t;
typedef unsigned int u32t;

#define MFMA16 __builtin_amdgcn_mfma_f32_16x16x16f16

__device__ __forceinline__ float sigmf(float x) { return 1.0f / (1.0f + __expf(-x)); }
__device__ __forceinline__ float tanh_f(float x) { return 2.0f / (1.0f + __expf(-2.0f * x)) - 1.0f; }

// X[t][b][e] = (fp16) emb[sentence[b][t]][e]; one thread = 8 elements.
__global__ void prep_x_kernel(const int* __restrict__ sent,
                              const float* __restrict__ emb,
                              _Float16* __restrict__ X) {
  int gid = blockIdx.x * blockDim.x + threadIdx.x;  // 2,097,152 total
  int e8 = gid & 31;
  int row = gid >> 5;         // row = t*128 + b
  int b = row & 127;
  int t = row >> 7;
  int word = sent[b * T_ + t];
  const float* src = emb + (size_t)word * E_ + e8 * 8;
  float4 v0 = *(const float4*)(src);
  float4 v1 = *(const float4*)(src + 4);
  _Float16 o[8] = {(_Float16)v0.x, (_Float16)v0.y, (_Float16)v0.z, (_Float16)v0.w,
                   (_Float16)v1.x, (_Float16)v1.y, (_Float16)v1.z, (_Float16)v1.w};
  _Float16* dst = X + (size_t)row * E_ + e8 * 8;
  *(half4*)dst = *(half4*)o;
  *(half4*)(dst + 4) = *(half4*)(o + 4);
}

__global__ __launch_bounds__(512, 1) void lstm_kernel(
    const _Float16* __restrict__ X,
    const float* __restrict__ Wx, const float* __restrict__ Wh,
    const float* __restrict__ bias,
    _Float16* __restrict__ Hq, u32t* FlagA, u32t* FlagB, u32t* XccTab) {
  // LDS: Hs [16][HROW_] fp16 (16,512) | Rs float[4][512] (8,192) |
  // xl u32[128] (512) | go u32 | pcnt u32 = 25,224 used; padded to 96 KB.
  __shared__ __align__(16) char smem[98304];
  _Float16* Hs = (_Float16*)smem;
  float* Rs = (float*)(smem + 16512);
  u32t* xl = (u32t*)(smem + 24704);
  volatile u32t* goP = (volatile u32t*)(smem + 25216);
  u32t* pcntP = (u32t*)(smem + 25220);

  const int bid = blockIdx.x;
  const int d = bid & 7;    // domain: rows d*16 .. d*16+15 (one XCD, verified)
  const int s = bid >> 3;   // unit slice: units s*32 .. s*32+31
  const int tid = threadIdx.x;
  const int lane = tid & 63;
  const int wave = tid >> 6;      // 8 waves
  const int p16 = lane & 15;
  const int quad = lane >> 4;
  const int sg = wave & 3;        // unit subgroup (8 units)
  const int kh = wave >> 2;       // 0: exchange + h[0,256) + epilogue
                                  // 1: x-GEMM + h[256,512)

  // ---- one-time XCD-mapping probe (gates the L2-local DATA path) ----
  // hwreg(HW_REG_XCC_ID=20, offset=0, size=32) -> imm = (31<<11)|20 = 63508
  if (tid == 0) {
    *goP = 0u;
    *pcntP = 0u;
    u32t myx = (u32t)__builtin_amdgcn_s_getreg(63508) & 0xFFu;
    __hip_atomic_store(XccTab + bid, 0x5A5A0000u | myx, __ATOMIC_RELAXED,
                       __HIP_MEMORY_SCOPE_AGENT);
  }
  if (wave == 0) {
    u32t v0, v1;
    for (;;) {
      v0 = __hip_atomic_load(XccTab + lane, __ATOMIC_RELAXED,
                             __HIP_MEMORY_SCOPE_AGENT);
      v1 = __hip_atomic_load(XccTab + 64 + lane, __ATOMIC_RELAXED,
                             __HIP_MEMORY_SCOPE_AGENT);
      if (__all(((v0 >> 16) == 0x5A5Au) & ((v1 >> 16) == 0x5A5Au))) break;
      __builtin_amdgcn_s_sleep(8);
    }
    xl[lane] = v0;
    xl[lane + 64] = v1;
  }
  __syncthreads();
  int fastv;
  {
    const u32t ref = xl[d];
    bool dom = true;
    for (int j = 1; j < 16; ++j) dom = dom && (xl[d + 8 * j] == ref);
    bool sane = false;  // getreg sanity: a constant-reading getreg -> slow
    const u32t z0 = xl[0];
    for (int e = 1; e < 128; ++e) sane = sane || (xl[e] != z0);
    fastv = (dom && sane) ? 1 : 0;
  }
  const bool fastp = (bool)__builtin_amdgcn_readfirstlane(fastv);

  // ---- one-time: gather this wave's B-fragments into VGPRs ----
  // kh0: 16 h-blocks (cols 0..255)   -> b0r[i], kb = 16+i,  i in [0,16)
  // kh1: 16 x-blocks + 16 h-blocks (cols 256..511)
  //      -> b0r[i]: i<16: kb = i (x); i>=16: kb = 16+i (h hi), i in [0,32)
  const int C0 = ((p16 >> 3) & 1) * 512 + s * 32 + sg * 8 + (p16 & 7);  // i/f
  const int C1 = C0 + 1024;                                             // g/o
  half4 b0r[32], b1r[32];
  if (kh == 0) {
#pragma unroll
    for (int i = 0; i < 16; ++i) {
      int kb = 16 + i;
#pragma unroll
      for (int j = 0; j < 4; ++j) {
        int gk = kb * 16 + quad * 4 + j;
        b0r[i][j] = (_Float16)Wh[(size_t)(gk - E_) * 2048 + C0];
        b1r[i][j] = (_Float16)Wh[(size_t)(gk - E_) * 2048 + C1];
      }
    }
  } else {
#pragma unroll
    for (int i = 0; i < 32; ++i) {
      int kb = (i < 16) ? i : (16 + i);
#pragma unroll
      for (int j = 0; j < 4; ++j) {
        int gk = kb * 16 + quad * 4 + j;
        float w0 = (gk < E_) ? Wx[(size_t)gk * 2048 + C0]
                             : Wh[(size_t)(gk - E_) * 2048 + C0];
        float w1 = (gk < E_) ? Wx[(size_t)gk * 2048 + C1]
                             : Wh[(size_t)(gk - E_) * 2048 + C1];
        b0r[i][j] = (_Float16)w0;
        b1r[i][j] = (_Float16)w1;
      }
    }
  }

  const bool lo = (p16 < 8);
  const int uo = p16 & 7;
  const int gu = s * 32 + sg * 8 + uo;               // global unit id
  const float bias0 = bias[(lo ? 0 : 512) + gu];     // i or f
  const float bias1 = bias[(lo ? 1024 : 1536) + gu]; // g or o

  float cst[4] = {0.f, 0.f, 0.f, 0.f};  // c-state (kh0 waves, lo lanes)

  const int brow = d * 16 + p16;   // A-frag batch row
  const int ko = quad * 4;

  for (int t = 0; t < T_; ++t) {
    const int pin = t & 1, pout = pin ^ 1;

    floatx4 acc0 = {0.f, 0.f, 0.f, 0.f};
    floatx4 acc1 = {0.f, 0.f, 0.f, 0.f};

    u32t gv = (u32t)t;  // gate value; ==t after the exchange gate passes

    if (kh == 1) {
      // ---- x-GEMM (kh1 only): 16 K16-blocks ----
      const _Float16* xr = X + ((size_t)t * B_ + brow) * E_ + ko;
#pragma unroll
      for (int i = 0; i < 16; ++i) {
        half4 a = *(const half4*)(xr + i * 16);
        acc0 = MFMA16(a, b0r[i], acc0, 0, 0, 0);
        acc1 = MFMA16(a, b1r[i], acc1, 0, 0, 0);
      }
    } else if (t > 0) {
      // ---- exchange (kh0 only): gate + bulk + stage, overlaps kh1's x ----
      const u32t tgt = (u32t)t;
      if (wave == 0) {
        // wave 0 is the sole poller (16 lanes, 16 distinct flag words).
        u32t v;
        if (fastp) {
          u32t* fa = FlagA + (size_t)(pin * 8 + d) * 16;
          const u32t* fb = FlagB + (size_t)(pin * 8 + d) * 16;
          int budget = 6;
          for (;;) {
            if (budget > 0) {
              // atomic RMW add-0 sc0: executes at the owning cache,
              // returns the authoritative current value.
              u32t old = tgt;
              if (lane < 16) {
                u32t* ap = fa + lane;
                asm volatile(
                    "global_atomic_add %0, %1, %2, off sc0\n\t"
                    "s_waitcnt vmcnt(0)"
                    : "=&v"(old) : "v"(ap), "v"(0u) : "memory");
              }
              v = old;
            } else {
              v = (lane < 16)
                      ? __hip_atomic_load(fb + lane, __ATOMIC_RELAXED,
                                          __HIP_MEMORY_SCOPE_AGENT)
                      : tgt;
            }
            if (__all(v == tgt)) break;
            --budget;
            if (budget < 4) __builtin_amdgcn_s_sleep(1);
          }
        } else {
          const u32t* fb = FlagB + (size_t)(pin * 8 + d) * 16;
          for (;;) {
            v = (lane < 16)
                    ? __hip_atomic_load(fb + lane, __ATOMIC_RELAXED,
                                        __HIP_MEMORY_SCOPE_AGENT)
                    : tgt;
            if (__all(v == tgt)) break;
            __builtin_amdgcn_s_sleep(1);
          }
        }
        gv = v;             // == tgt on every lane
        if (lane == 0) *goP = tgt;   // LDS release for waves 1-3
      } else {
        // waves 1-3: LDS gate (wave0 wrote go=t after data-safe flag).
        u32t g;
        do { g = *goP; } while (g < tgt);
        gv = g;             // == tgt (same-WG barriers bound the step)
      }
      const size_t dep = (size_t)(gv >> 16);  // always 0; addr dependency

      // bulk: 4 rows/wave (rows wave*4 .. wave*4+3), 8 chunks of 512B
      const _Float16* hq =
          Hq + ((size_t)(pin * 8 + d) * 16 + wave * 4) * 512 + dep;
      u64t hv[8];
      if (fastp) {
        // ONE asm block: 8 pipelined sc0 loads (imm offsets), one vmcnt(0).
        const u64t* hqb = (const u64t*)hq + lane;
        u64t h0, h1, h2, h3, h4, h5, h6, h7;
        asm volatile(
            "global_load_dwordx2 %0, %8, off sc0\n\t"
            "global_load_dwordx2 %1, %8, off offset:512 sc0\n\t"
            "global_load_dwordx2 %2, %8, off offset:1024 sc0\n\t"
            "global_load_dwordx2 %3, %8, off offset:1536 sc0\n\t"
            "global_load_dwordx2 %4, %8, off offset:2048 sc0\n\t"
            "global_load_dwordx2 %5, %8, off offset:2560 sc0\n\t"
            "global_load_dwordx2 %6, %8, off offset:3072 sc0\n\t"
            "global_load_dwordx2 %7, %8, off offset:3584 sc0\n\t"
            "s_waitcnt vmcnt(0)"
            : "=&v"(h0), "=&v"(h1), "=&v"(h2), "=&v"(h3),
              "=&v"(h4), "=&v"(h5), "=&v"(h6), "=&v"(h7)
            : "v"(hqb)
            : "memory");
        hv[0] = h0; hv[1] = h1; hv[2] = h2; hv[3] = h3;
        hv[4] = h4; hv[5] = h5; hv[6] = h6; hv[7] = h7;
      } else {
#pragma unroll
        for (int j = 0; j < 8; ++j) {
          size_t idx = (size_t)(j >> 1) * 128 + (j & 1) * 64 + lane;
          hv[j] = __hip_atomic_load((const u64t*)hq + idx, __ATOMIC_RELAXED,
                                    __HIP_MEMORY_SCOPE_AGENT);
        }
      }
#pragma unroll
      for (int j = 0; j < 8; ++j) {
        int r = wave * 4 + (j >> 1), half = j & 1;
        *(u64t*)(Hs + r * HROW_ + half * 256 + lane * 4) = hv[j];
      }
    }
    __syncthreads();  // B2: slab ready + x partial-accs in flight

    if (t > 0) {
      // ---- h-GEMM from slab: kh0 -> cols [0,256), kh1 -> [256,512) ----
#pragma unroll
      for (int i = 0; i < 16; ++i) {
        int hk = kh * 16 + i;
        half4 a = *(const half4*)(Hs + p16 * HROW_ + hk * 16 + ko);
        const int wi = (kh == 0) ? i : (16 + i);
        acc0 = MFMA16(a, b0r[wi], acc0, 0, 0, 0);
        acc1 = MFMA16(a, b1r[wi], acc1, 0, 0, 0);
      }
    }

    // ---- kh1 partials -> Rs ----
    if (kh == 1) {
      float* wb = Rs + sg * 512;
      *(floatx4*)(wb + lane * 4) = acc0;
      *(floatx4*)(wb + 256 + lane * 4) = acc1;
    }
    __syncthreads();  // B3: partials ready. kh1 then free-runs to t+1.

    // ---- epilogue (kh0): reduce, gates, fp16 publish, flag ----
    if (kh == 0) {
      const float* rb = Rs + sg * 512;
      floatx4 z0v = acc0 + *(const floatx4*)(rb + lane * 4);
      floatx4 z1v = acc1 + *(const floatx4*)(rb + 256 + lane * 4);
#pragma unroll
      for (int r = 0; r < 4; ++r) {
        float z0 = z0v[r] + bias0;  // i (lo) / f (hi)
        float z1 = z1v[r] + bias1;  // g (lo) / o (hi)
        float s0 = sigmf(z0);
        float s1 = lo ? tanh_f(z1) : sigmf(z1);
        float prod = s0 * s1;                          // i*g on lo lanes
        float fg = __shfl_xor(lo ? prod : s0, 8, 64);  // lo receives f
        float og = __shfl_xor(s1, 8, 64);              // lo receives o
        if (lo) {
          float cn = fg * cst[r] + prod;
          cst[r] = cn;
          float h = og * tanh_f(cn);
          int rowl = quad * 4 + r;                     // local row in domain
          _Float16 hf16 = (_Float16)h;
          unsigned short hb = __builtin_bit_cast(unsigned short, hf16);
          unsigned short* hp =
              (unsigned short*)(Hq +
                                ((size_t)(pout * 8 + d) * 16 + rowl) * 512 + gu);
          if (fastp) {
            // plain store: L1 write-through -> dirty in local XCD-L2
            *hp = hb;
          } else {
            __hip_atomic_store(hp, hb, __ATOMIC_RELAXED,
                               __HIP_MEMORY_SCOPE_AGENT);
          }
        }
      }

      // ---- R22 publish: per-wave drain + LDS counter (replaces B4) ----
      // Each kh0 wave drains ITS OWN h-stores, then increments pcnt; the
      // 4th arrival (old == 4t+3) publishes. LDS dependency orders the
      // publish after all four drains — same guarantee B4 gave, without
      // blocking kh1 (which free-runs into x-GEMM(t+1) after B3).
      asm volatile("s_waitcnt vmcnt(0)" ::: "memory");
      __builtin_amdgcn_sched_barrier(0);
      if (lane == 0) {
        u32t old = atomicAdd(pcntP, 1u);
        if (old == (u32t)(4 * t + 3)) {
          size_t fo = (size_t)(pout * 8 + d) * 16 + s;
          if (fastp) {
            u32t* ap = FlagA + fo;
            u32t nv = (u32t)(t + 1);
            asm volatile("global_atomic_swap %0, %1, off"
                         :: "v"(ap), "v"(nv) : "memory");
          }
          __hip_atomic_store(FlagB + fo, (u32t)(t + 1), __ATOMIC_RELAXED,
                             __HIP_MEMORY_SCOPE_AGENT);  // progress channel
        }
      }
    }
    // (B4 removed)
  }
}

// MLP head: one block per batch row. h(512)->relu 128->relu 64->sigmoid 1.
// T=512 even -> final h in Hq parity 0. Kernel boundary orders prior stores
// (end-of-dispatch agent release writes back dirty L2 lines).
__global__ void head_kernel(const _Float16* __restrict__ Hq,
                            const float* __restrict__ W1, const float* __restrict__ b1,
                            const float* __restrict__ W2, const float* __restrict__ b2,
                            const float* __restrict__ W3, const float* __restrict__ b3,
                            float* __restrict__ out) {
  __shared__ float hs[512];
  __shared__ float h1[128];
  __shared__ float h2[64];
  int row = blockIdx.x;
  int tid = threadIdx.x;  // 128 threads
  int dd = row >> 4, rr = row & 15;
  const _Float16* hrow = Hq + ((size_t)dd * 16 + rr) * 512;
  for (int k = tid; k < 512; k += 128) hs[k] = (float)hrow[k];
  __syncthreads();
  float a = b1[tid];
  for (int k = 0; k < 512; ++k) a += hs[k] * W1[k * 128 + tid];
  h1[tid] = fmaxf(a, 0.0f);
  __syncthreads();
  if (tid < 64) {
    float a2 = b2[tid];
    for (int k = 0; k < 128; ++k) a2 += h1[k] * W2[k * 64 + tid];
    h2[tid] = fmaxf(a2, 0.0f);
  }
  __syncthreads();
  if (tid == 0) {
    float a3 = b3[0];
    for (int k = 0; k < 64; ++k) a3 += h2[k] * W3[k];
    out[row] = 1.0f / (1.0f + __expf(-a3));
  }
}

extern "C" void kernel_launch(void* const* d_in, const int* in_sizes, int n_in,
                              void* d_out, int out_size, void* d_ws, size_t ws_size,
                              hipStream_t stream) {
  const int* sent = (const int*)d_in[0];
  const float* emb = (const float*)d_in[1];
  const float* Wx = (const float*)d_in[2];
  const float* Wh = (const float*)d_in[3];
  const float* b = (const float*)d_in[4];
  const float* W1 = (const float*)d_in[5];
  const float* b1 = (const float*)d_in[6];
  const float* W2 = (const float*)d_in[7];
  const float* b2 = (const float*)d_in[8];
  const float* W3 = (const float*)d_in[9];
  const float* b3 = (const float*)d_in[10];
  float* out = (float*)d_out;

  char* ws = (char*)d_ws;
  _Float16* X = (_Float16*)(ws);
  _Float16* Hq = (_Float16*)(ws + (size_t)33554432);
  u32t* FlagA = (u32t*)(ws + (size_t)33554432 + 262144);
  u32t* FlagB = (u32t*)(ws + (size_t)33554432 + 263168);
  u32t* XccTab = (u32t*)(ws + (size_t)33554432 + 264192);

  // Zero FlagA+FlagB+XccTab (contiguous 2,560 B) every launch:
  // removes the first-launch garbage hazard; 0 never matches t in [1,512].
  hipMemsetAsync(FlagA, 0, 2560, stream);
  prep_x_kernel<<<8192, 256, 0, stream>>>(sent, emb, X);
  lstm_kernel<<<NWG_, 512, 0, stream>>>(X, Wx, Wh, b, Hq, FlagA, FlagB, XccTab);
  head_kernel<<<128, 128, 0, stream>>>(Hq, W1, b1, W2, b2, W3, b3, out);
}